// Round 6
// baseline (2373.739 us; speedup 1.0000x reference)
//
#include <hip/hip_runtime.h>
#include <math.h>

#define T 64
#define H 256

typedef _Float16 f16;
typedef _Float16 f16x8 __attribute__((ext_vector_type(8)));
typedef float f32x4 __attribute__((ext_vector_type(4)));

__device__ __forceinline__ float sigm(float x) { return 1.f / (1.f + __expf(-x)); }
__device__ __forceinline__ float ftanh(float x) { return 1.f - 2.f / (__expf(2.f * x) + 1.f); }

// ---------------------------------------------------------------------------
// k_prep_u: coalesced frag-ordering of the 65 scan-LSTM U matrices into f16.
//   Uf2 flat idx = ((((lstm*8 + w)*8 + kt)*8 + ct)*64 + l)*8 + e
//   = U[k = kt*32 + (l>>4)*8 + e][col = g*256 + w*32 + nt*16 + (l&15)]
//   with g = ct>>1, nt = ct&1.
// ---------------------------------------------------------------------------
__global__ __launch_bounds__(256) void k_prep_u(
    const float* __restrict__ Uxp, const float* __restrict__ Uxn,
    const float* __restrict__ Uy, f16* __restrict__ Uf2)
{
  __shared__ f16 lds[32][1024];  // 64 KB
  const int tid = threadIdx.x;
  const int lstm = blockIdx.x >> 3, kt = blockIdx.x & 7;
  const float* src = (lstm < 32) ? (Uxp + (size_t)lstm * 262144)
                   : (lstm < 64) ? (Uxn + (size_t)(lstm - 32) * 262144)
                   : Uy;
  const int k0 = kt * 32;
  for (int i = tid; i < 32 * 1024; i += 256) {
    const int row = i >> 10, col = i & 1023;
    lds[row][col] = (f16)src[(size_t)(k0 + row) * 1024 + col];
  }
  __syncthreads();
  const int l = tid & 63, c0 = tid >> 6;
  for (int c = c0; c < 64; c += 4) {
    const int w = c >> 3, ct = c & 7, g = ct >> 1, nt = ct & 1;
    f16x8 v;
    #pragma unroll
    for (int e = 0; e < 8; ++e)
      v[e] = lds[(l >> 4) * 8 + e][g * 256 + w * 32 + nt * 16 + (l & 15)];
    *(f16x8*)(Uf2 + (((((size_t)lstm * 8 + w) * 8 + kt) * 8 + ct) * 64 + l) * 8) = v;
  }
}

// ---------------------------------------------------------------------------
// k_prep_wmi: pack all MI-LSTM recurrent weights into one f16 buffer.
// Column space c in [0,2304): 0-1023 Um, 1024-1535 Upa, 1536-2047 Una,
// 2048-2303 Wa.  Wmi[((kc*2304) + c)*8 + e] = W[k = kc*8+e][scol]
// ---------------------------------------------------------------------------
__global__ __launch_bounds__(64) void k_prep_wmi(
    const float* __restrict__ Um, const float* __restrict__ Upa,
    const float* __restrict__ Una, const float* __restrict__ Wa,
    f16* __restrict__ Wmi)
{
  const int l = threadIdx.x;
  const int c = blockIdx.x * 2 + (l >> 5);
  const int kc = l & 31;
  const float* src; int scol, ld;
  if (c < 1024)      { src = Um;  scol = c;        ld = 1024; }
  else if (c < 1536) { src = Upa; scol = c - 1024; ld = 512;  }
  else if (c < 2048) { src = Una; scol = c - 1536; ld = 512;  }
  else               { src = Wa;  scol = c - 2048; ld = 256;  }
  f16x8 v;
  #pragma unroll
  for (int e = 0; e < 8; ++e) v[e] = (f16)src[(size_t)(kc * 8 + e) * ld + scol];
  *(f16x8*)(Wmi + ((size_t)kc * 2304 + c) * 8) = v;
}

// ---------------------------------------------------------------------------
// k_prep_x: X[b][t][f] -> Xt[s][f][t][b]
// ---------------------------------------------------------------------------
__global__ __launch_bounds__(512) void k_prep_x(
    const float* __restrict__ Xp, const float* __restrict__ Xn, float* __restrict__ Xt)
{
  const int s = blockIdx.x >> 5, f = blockIdx.x & 31;
  const float* X = s ? Xn : Xp;
  for (int i = threadIdx.x; i < 2048; i += 512) {
    const int t = i >> 5, b = i & 31;
    Xt[((size_t)(s * 32 + f) * 64 + t) * 32 + b] = X[((size_t)b * 64 + t) * 32 + f];
  }
}

// ---------------------------------------------------------------------------
// k_prep_yg0: yg0t[t][col][b] = Y[b,t,:] @ Wy + by
// ---------------------------------------------------------------------------
__global__ __launch_bounds__(1024) void k_prep_yg0(
    const float* __restrict__ Y, const float* __restrict__ Wy,
    const float* __restrict__ by, float* __restrict__ yg0t)
{
  const int t = blockIdx.x, col = threadIdx.x;
  float wv[10];
  #pragma unroll
  for (int i = 0; i < 10; ++i) wv[i] = Wy[i * 1024 + col];
  const float bv = by[col];
  for (int b = 0; b < 32; ++b) {
    float a = bv;
    #pragma unroll
    for (int i = 0; i < 10; ++i) a += Y[((size_t)b * 64 + t) * 10 + i] * wv[i];
    yg0t[((size_t)t * 1024 + col) * 32 + b] = a;
  }
}

// ---------------------------------------------------------------------------
// k_scan: barrier-free streaming LSTM scan. One block per LSTM (65 blocks,
// 512 thr = 8 waves); U streamed from L2 in fragment order every step; h
// block-local in LDS frag layout (f16). Feature blocks write their h
// sequence to a PRIVATE hseq slab (plain f16 stores — no atomics, nothing
// contended in the end-of-step vmcnt drain). k_mean reduces afterwards.
// ---------------------------------------------------------------------------
__global__ __launch_bounds__(512, 2) void k_scan(
    const float* __restrict__ Xt,
    const float* __restrict__ Wxp, const float* __restrict__ bxp,
    const float* __restrict__ Wxn, const float* __restrict__ bxn,
    const f16* __restrict__ Uf2, const float* __restrict__ yg0t,
    float* __restrict__ Yh, f16* __restrict__ hseq)
{
  __shared__ __align__(16) f16 hfrag[2 * 8 * 64 * 8];  // [mt][kt][lane][e], 16 KB
  const int tid = threadIdx.x;
  const int w = tid >> 6, l = tid & 63;
  const int cl = l & 15, lq = l >> 4;
  const int lstm = blockIdx.x;
  const bool isY = (lstm == 64);
  const int s = (lstm >= 32 && !isY) ? 1 : 0;
  const int f = lstm & 31;

  const f16* UB = Uf2 + ((size_t)(lstm * 8 + w) * 64) * 512 + (size_t)l * 8;

  float Wc[4][2], Bc[4][2];
  const float* xrow = nullptr;
  if (!isY) {
    const float* Wf = (s ? Wxn : Wxp) + (size_t)f * 1024;
    const float* bf = (s ? bxn : bxp) + (size_t)f * 1024;
    #pragma unroll
    for (int g = 0; g < 4; ++g)
      #pragma unroll
      for (int nt = 0; nt < 2; ++nt) {
        const int col = g * 256 + w * 32 + nt * 16 + cl;
        Wc[g][nt] = Wf[col]; Bc[g][nt] = bf[col];
      }
    xrow = Xt + (size_t)(s * 32 + f) * 2048;
  }
  f16* hout = hseq + (size_t)lstm * (64 * 32 * 256);

  float c[2][2][4];  // [nt][mt][j]
  #pragma unroll
  for (int nt = 0; nt < 2; ++nt)
    #pragma unroll
    for (int mt = 0; mt < 2; ++mt)
      #pragma unroll
      for (int j = 0; j < 4; ++j) c[nt][mt][j] = 0.f;

  for (int i = tid; i < 1024; i += 512) ((uint4*)hfrag)[i] = uint4{0, 0, 0, 0};
  __syncthreads();

  for (int t = 0; t < T; ++t) {
    f16x8 Uc[8], Un[8];
    #pragma unroll
    for (int ct = 0; ct < 8; ++ct) Uc[ct] = *(const f16x8*)(UB + ct * 512);

    f32x4 acc[8][2];
    #pragma unroll
    for (int ct = 0; ct < 8; ++ct) { acc[ct][0] = f32x4{0,0,0,0}; acc[ct][1] = f32x4{0,0,0,0}; }

    #pragma unroll
    for (int kt = 0; kt < 8; ++kt) {
      if (kt < 7) {
        #pragma unroll
        for (int ct = 0; ct < 8; ++ct)
          Un[ct] = *(const f16x8*)(UB + ((kt + 1) * 8 + ct) * 512);
      }
      const f16x8 a0 = *(const f16x8*)(hfrag + (0 * 8 + kt) * 512 + l * 8);
      const f16x8 a1 = *(const f16x8*)(hfrag + (1 * 8 + kt) * 512 + l * 8);
      #pragma unroll
      for (int ct = 0; ct < 8; ++ct) {
        acc[ct][0] = __builtin_amdgcn_mfma_f32_16x16x32_f16(a0, Uc[ct], acc[ct][0], 0, 0, 0);
        acc[ct][1] = __builtin_amdgcn_mfma_f32_16x16x32_f16(a1, Uc[ct], acc[ct][1], 0, 0, 0);
      }
      #pragma unroll
      for (int ct = 0; ct < 8; ++ct) Uc[ct] = Un[ct];
    }
    __syncthreads();   // all waves done reading hfrag

    #pragma unroll
    for (int mt = 0; mt < 2; ++mt) {
      float4 xq;
      if (!isY) xq = *(const float4*)(xrow + t * 32 + mt * 16 + lq * 4);
      #pragma unroll
      for (int nt = 0; nt < 2; ++nt) {
        float4 yq[4];
        if (isY) {
          #pragma unroll
          for (int g = 0; g < 4; ++g) {
            const int col = g * 256 + w * 32 + nt * 16 + cl;
            yq[g] = *(const float4*)(yg0t + ((size_t)t * 1024 + col) * 32 + mt * 16 + lq * 4);
          }
        }
        const int n = w * 32 + nt * 16 + cl;
        #pragma unroll
        for (int j = 0; j < 4; ++j) {
          const int b = mt * 16 + lq * 4 + j;
          float p0, p1, p2, p3;
          if (isY) {
            p0 = acc[0 * 2 + nt][mt][j] + ((const float*)&yq[0])[j];
            p1 = acc[1 * 2 + nt][mt][j] + ((const float*)&yq[1])[j];
            p2 = acc[2 * 2 + nt][mt][j] + ((const float*)&yq[2])[j];
            p3 = acc[3 * 2 + nt][mt][j] + ((const float*)&yq[3])[j];
          } else {
            const float x = ((const float*)&xq)[j];
            p0 = acc[0 * 2 + nt][mt][j] + x * Wc[0][nt] + Bc[0][nt];
            p1 = acc[1 * 2 + nt][mt][j] + x * Wc[1][nt] + Bc[1][nt];
            p2 = acc[2 * 2 + nt][mt][j] + x * Wc[2][nt] + Bc[2][nt];
            p3 = acc[3 * 2 + nt][mt][j] + x * Wc[3][nt] + Bc[3][nt];
          }
          const float ig = sigm(p0), fg = sigm(p1), gy = ftanh(p2), og = sigm(p3);
          c[nt][mt][j] = fg * c[nt][mt][j] + ig * gy;
          const float h = og * ftanh(c[nt][mt][j]);
          const int lanep = (lq * 4 + j) + (nt * 2 + (cl >> 3)) * 16;
          hfrag[(mt * 8 + w) * 512 + lanep * 8 + (cl & 7)] = (f16)h;
          if (isY) Yh[((size_t)b * T + t) * H + n] = h;
          else hout[(((size_t)t * 32 + b) * 256) + n] = (f16)h;
        }
      }
    }
    __syncthreads();
  }
}

// ---------------------------------------------------------------------------
// k_mean: feature mean. Ph[(b*T+t)*H+n] = mean_f hseq[f][t][b][n] (f=0..31),
// Nh from f=32..63. 2048 blocks x 256 thr, fully parallel, TLP-hidden.
// ---------------------------------------------------------------------------
__global__ __launch_bounds__(256) void k_mean(
    const f16* __restrict__ hseq, float* __restrict__ Ph, float* __restrict__ Nh)
{
  const int bt = blockIdx.x;        // b*T + t
  const int b = bt >> 6, t = bt & 63;
  const int n = threadIdx.x;
  const size_t base = (((size_t)t * 32 + b) * 256) + n;
  float s0 = 0.f, s1 = 0.f;
  #pragma unroll
  for (int f = 0; f < 32; ++f) {
    s0 += (float)hseq[(size_t)f        * (64 * 32 * 256) + base];
    s1 += (float)hseq[(size_t)(f + 32) * (64 * 32 * 256) + base];
  }
  Ph[(size_t)bt * 256 + n] = s0 * 0.03125f;
  Nh[(size_t)bt * 256 + n] = s1 * 0.03125f;
}

// ---------------------------------------------------------------------------
// k_xg: MI-LSTM input projections.
// ---------------------------------------------------------------------------
__global__ __launch_bounds__(1024) void k_xg(
    const float* __restrict__ Yh, const float* __restrict__ Ph, const float* __restrict__ Nh,
    const float* __restrict__ Wm, const float* __restrict__ bm,
    const float* __restrict__ Wpa, const float* __restrict__ bpa,
    const float* __restrict__ Wna, const float* __restrict__ bna,
    float* __restrict__ yg, float* __restrict__ pg, float* __restrict__ ng)
{
  __shared__ __align__(16) float A[8][768];
  const int tid = threadIdx.x;
  const int ro  = blockIdx.x * 8;

  for (int idx = tid; idx < 8 * 768; idx += 1024) {
    const int r = idx / 768, cc = idx % 768;
    const int row = ro + r;
    float v;
    if (cc < 256)      v = Yh[(size_t)row * H + cc];
    else if (cc < 512) v = Ph[(size_t)row * H + (cc - 256)];
    else               v = Nh[(size_t)row * H + (cc - 512)];
    A[r][cc] = v;
  }
  __syncthreads();

  float acc[8];
  #pragma unroll
  for (int r = 0; r < 8; ++r) acc[r] = bm[tid];
  for (int k = 0; k < H; k += 4) {
    const float w0 = Wm[(k + 0) * 1024 + tid];
    const float w1 = Wm[(k + 1) * 1024 + tid];
    const float w2 = Wm[(k + 2) * 1024 + tid];
    const float w3 = Wm[(k + 3) * 1024 + tid];
    #pragma unroll
    for (int r = 0; r < 8; ++r) {
      const float4 av = *(const float4*)&A[r][k];
      acc[r] += w0 * av.x + w1 * av.y + w2 * av.z + w3 * av.w;
    }
  }
  #pragma unroll
  for (int r = 0; r < 8; ++r) yg[(size_t)(ro + r) * 1024 + tid] = acc[r];

  const int col = tid & 511;
  const float* Wx = (tid < 512) ? Wpa : Wna;
  const float* bx = (tid < 512) ? bpa : bna;
  float* outp     = (tid < 512) ? pg : ng;
  const int aoff  = (tid < 512) ? 256 : 512;
  #pragma unroll
  for (int r = 0; r < 8; ++r) acc[r] = bx[col];
  for (int k = 0; k < H; k += 4) {
    const float w0 = Wx[(k + 0) * 512 + col];
    const float w1 = Wx[(k + 1) * 512 + col];
    const float w2 = Wx[(k + 2) * 512 + col];
    const float w3 = Wx[(k + 3) * 512 + col];
    #pragma unroll
    for (int r = 0; r < 8; ++r) {
      const float4 av = *(const float4*)&A[r][aoff + k];
      acc[r] += w0 * av.x + w1 * av.y + w2 * av.z + w3 * av.w;
    }
  }
  #pragma unroll
  for (int r = 0; r < 8; ++r) outp[(size_t)(ro + r) * 512 + col] = acc[r];
}

// ---------------------------------------------------------------------------
// k_mi v5: one block per batch (32 blocks, 1024 thr), NO cross-block sync.
// Phase1 streams the packed 1.18 MB f16 weight buffer; phase2 does gates /
// cell-attention softmax / state update with in-block reductions.
// ---------------------------------------------------------------------------
__global__ __launch_bounds__(1024, 1) void k_mi(
    const float* __restrict__ yg, const float* __restrict__ pg, const float* __restrict__ ng,
    const f16* __restrict__ Wmi, const float* __restrict__ ba,
    float* __restrict__ Hm)
{
  __shared__ float g_all[2304];
  __shared__ __align__(16) f16 h_lds[256];
  __shared__ __align__(16) f16 c_lds[256];
  __shared__ float red[3][4];
  const int tid = threadIdx.x;
  const int b = blockIdx.x;

  if (tid < 256) { h_lds[tid] = (f16)0.f; c_lds[tid] = (f16)0.f; }
  const float bav = (tid < 256) ? ba[tid] : 0.f;
  float creg = 0.f;
  __syncthreads();

  for (int t = 0; t < T; ++t) {
    const size_t row = (size_t)b * T + t;

    float pre[8];
    if (tid < 256) {
      #pragma unroll
      for (int g = 0; g < 4; ++g) pre[g] = yg[row * 1024 + g * 256 + tid];
      pre[4] = pg[row * 512 + tid];       pre[5] = pg[row * 512 + 256 + tid];
      pre[6] = ng[row * 512 + tid];       pre[7] = ng[row * 512 + 256 + tid];
    }

    for (int c = tid; c < 2304; c += 1024) {
      const f16* hsrc = (c >= 2048) ? c_lds : h_lds;
      const f16* wcol = Wmi + (size_t)c * 8;
      float acc = 0.f;
      #pragma unroll 8
      for (int kc = 0; kc < 32; ++kc) {
        const f16x8 wv = *(const f16x8*)(wcol + (size_t)kc * 2304 * 8);
        const f16x8 hv = *(const f16x8*)(hsrc + kc * 8);
        #pragma unroll
        for (int e = 0; e < 8; ++e) acc += (float)wv[e] * (float)hv[e];
      }
      g_all[c] = acc;
    }
    __syncthreads();

    float l0 = 0.f, l1 = 0.f, l2 = 0.f, fg = 0.f, og = 0.f;
    if (tid < 256) {
      const int n = tid;
      const float gi = sigm(g_all[n]            + pre[0]);
      fg             = sigm(g_all[256 + n]      + pre[1]);
      const float gy = ftanh(g_all[512 + n]     + pre[2]);
      og             = sigm(g_all[768 + n]      + pre[3]);
      const float ip = sigm(g_all[1024 + n]     + pre[4]);
      const float cp = ftanh(g_all[1280 + n]    + pre[5]);
      const float in = sigm(g_all[1536 + n]     + pre[6]);
      const float cn = ftanh(g_all[1792 + n]    + pre[7]);
      const float att = ftanh(g_all[2048 + n]   + bav);
      l0 = gi * gy; l1 = ip * cp; l2 = in * cn;
      float v0 = l0 * att, v1 = l1 * att, v2 = l2 * att;
      #pragma unroll
      for (int off = 32; off; off >>= 1) {
        v0 += __shfl_down(v0, off);
        v1 += __shfl_down(v1, off);
        v2 += __shfl_down(v2, off);
      }
      if ((tid & 63) == 0) {
        red[0][tid >> 6] = v0; red[1][tid >> 6] = v1; red[2][tid >> 6] = v2;
      }
    }
    __syncthreads();

    if (tid < 256) {
      const int n = tid;
      const float s0 = red[0][0] + red[0][1] + red[0][2] + red[0][3];
      const float s1 = red[1][0] + red[1][1] + red[1][2] + red[1][3];
      const float s2 = red[2][0] + red[2][1] + red[2][2] + red[2][3];
      const float m  = fmaxf(s0, fmaxf(s1, s2));
      const float e0 = __expf(s0 - m), e1 = __expf(s1 - m), e2 = __expf(s2 - m);
      const float lt = (e0 * l0 + e1 * l1 + e2 * l2) / (e0 + e1 + e2);
      creg = fg * creg + lt;
      const float h = og * ftanh(creg);
      h_lds[n] = (f16)h;
      c_lds[n] = (f16)creg;
      Hm[row * H + n] = h;
    }
    __syncthreads();
  }
}

// ---------------------------------------------------------------------------
// k_att: temporal additive attention + linear head.
// ---------------------------------------------------------------------------
__global__ __launch_bounds__(256) void k_att(
    const float* __restrict__ Hm, const float* __restrict__ Watt, const float* __restrict__ batt,
    const float* __restrict__ vatt, const float* __restrict__ Wlin, const float* __restrict__ blin,
    float* __restrict__ out)
{
  __shared__ __align__(16) float hm8[8][H];
  __shared__ float vred[8][4];
  __shared__ float s_lds[T];
  __shared__ float alpha_lds[T];
  __shared__ float red4[4];
  const int n = threadIdx.x;
  const int b = blockIdx.x;
  const float bn = batt[n], vn = vatt[n];

  for (int t0 = 0; t0 < T; t0 += 8) {
    __syncthreads();
    #pragma unroll
    for (int r = 0; r < 8; ++r) hm8[r][n] = Hm[((size_t)b * T + t0 + r) * H + n];
    __syncthreads();
    float acc[8];
    #pragma unroll
    for (int r = 0; r < 8; ++r) acc[r] = bn;
    for (int k = 0; k < H; k += 4) {
      const float w0 = Watt[(k + 0) * H + n];
      const float w1 = Watt[(k + 1) * H + n];
      const float w2 = Watt[(k + 2) * H + n];
      const float w3 = Watt[(k + 3) * H + n];
      #pragma unroll
      for (int r = 0; r < 8; ++r) {
        const float4 hv = *(const float4*)&hm8[r][k];
        acc[r] += w0 * hv.x + w1 * hv.y + w2 * hv.z + w3 * hv.w;
      }
    }
    #pragma unroll
    for (int r = 0; r < 8; ++r) {
      float v = tanhf(acc[r]) * vn;
      for (int off = 32; off; off >>= 1) v += __shfl_down(v, off);
      if ((n & 63) == 0) vred[r][n >> 6] = v;
    }
    __syncthreads();
    if (n < 8) s_lds[t0 + n] = vred[n][0] + vred[n][1] + vred[n][2] + vred[n][3];
  }
  __syncthreads();

  if (n < T) {
    const float sv = s_lds[n];
    float m = sv;
    for (int off = 32; off; off >>= 1) m = fmaxf(m, __shfl_xor(m, off));
    const float e = expf(sv - m);
    float sum = e;
    for (int off = 32; off; off >>= 1) sum += __shfl_xor(sum, off);
    alpha_lds[n] = e / sum;
  }
  __syncthreads();

  float acc = 0.f;
  for (int t = 0; t < T; ++t) acc += alpha_lds[t] * Hm[((size_t)b * T + t) * H + n];
  float p = acc * Wlin[n];
  for (int off = 32; off; off >>= 1) p += __shfl_down(p, off);
  if ((n & 63) == 0) red4[n >> 6] = p;
  __syncthreads();
  if (n == 0) out[b] = fmaxf(red4[0] + red4[1] + red4[2] + red4[3] + blin[0], 0.f);
}

// ---------------------------------------------------------------------------
extern "C" void kernel_launch(void* const* d_in, const int* in_sizes, int n_in,
                              void* d_out, int out_size, void* d_ws, size_t ws_size,
                              hipStream_t stream) {
  const float* Yin  = (const float*)d_in[0];
  const float* Xp   = (const float*)d_in[1];
  const float* Xn   = (const float*)d_in[2];
  const float* Wy   = (const float*)d_in[3];
  const float* Uy   = (const float*)d_in[4];
  const float* by   = (const float*)d_in[5];
  const float* Wxp  = (const float*)d_in[6];
  const float* Uxp  = (const float*)d_in[7];
  const float* bxp  = (const float*)d_in[8];
  const float* Wxn  = (const float*)d_in[9];
  const float* Uxn  = (const float*)d_in[10];
  const float* bxn  = (const float*)d_in[11];
  const float* Wm   = (const float*)d_in[12];
  const float* Um   = (const float*)d_in[13];
  const float* bm   = (const float*)d_in[14];
  const float* Wpa  = (const float*)d_in[15];
  const float* Upa  = (const float*)d_in[16];
  const float* bpa  = (const float*)d_in[17];
  const float* Wna  = (const float*)d_in[18];
  const float* Una  = (const float*)d_in[19];
  const float* bna  = (const float*)d_in[20];
  const float* Wa   = (const float*)d_in[21];
  const float* ba   = (const float*)d_in[22];
  const float* Watt = (const float*)d_in[23];
  const float* batt = (const float*)d_in[24];
  const float* vatt = (const float*)d_in[25];
  const float* Wlin = (const float*)d_in[26];
  const float* blin = (const float*)d_in[27];

  float* ws = (float*)d_ws;
  float*    Yh    = ws;                         // 524288
  float*    Ph    = ws + 524288;                // 524288
  float*    Nh    = ws + 1048576;               // 524288
  float*    Hm    = ws + 1572864;               // 524288
  float*    yg    = ws + 2097152;               // 2097152
  float*    pg    = ws + 4194304;               // 1048576
  float*    ng    = ws + 5242880;               // 1048576
  float*    yg0t  = ws + 6291456;               // 2097152
  float*    Xt    = ws + 8388608;               // 131072
  f16*      Uf2   = (f16*)(ws + 8519680);       // 17039360 f16 (8519680 floats)
  f16*      Wmi   = (f16*)(ws + 17039360);      // 589824 f16 (294912 floats)
  f16*      hseq  = (f16*)(ws + 17334272);      // 64*64*32*256 f16 (16777216 floats)
  float*    out   = (float*)d_out;

  k_prep_u   <<<520, 256, 0, stream>>>(Uxp, Uxn, Uy, Uf2);
  k_prep_wmi <<<1152, 64, 0, stream>>>(Um, Upa, Una, Wa, Wmi);
  k_prep_x   <<<64, 512, 0, stream>>>(Xp, Xn, Xt);
  k_prep_yg0 <<<64, 1024, 0, stream>>>(Yin, Wy, by, yg0t);

  k_scan<<<65, 512, 0, stream>>>(Xt, Wxp, bxp, Wxn, bxn, Uf2, yg0t, Yh, hseq);
  k_mean<<<2048, 256, 0, stream>>>(hseq, Ph, Nh);
  k_xg  <<<256, 1024, 0, stream>>>(Yh, Ph, Nh, Wm, bm, Wpa, bpa, Wna, bna, yg, pg, ng);
  k_mi  <<<32, 1024, 0, stream>>>(yg, pg, ng, Wmi, ba, Hm);
  k_att <<<32, 256, 0, stream>>>(Hm, Watt, batt, vatt, Wlin, blin, out);
}

// Round 7
// 2353.903 us; speedup vs baseline: 1.0084x; 1.0084x over previous
//
#include <hip/hip_runtime.h>
#include <math.h>

#define T 64
#define H 256

typedef _Float16 f16;
typedef _Float16 f16x8 __attribute__((ext_vector_type(8)));
typedef float f32x4 __attribute__((ext_vector_type(4)));

__device__ __forceinline__ float sigm(float x) { return 1.f / (1.f + __expf(-x)); }
__device__ __forceinline__ float ftanh(float x) { return 1.f - 2.f / (__expf(2.f * x) + 1.f); }

// ---------------------------------------------------------------------------
// k_prep_u: coalesced frag-ordering of the 65 scan-LSTM U matrices into f16,
// 16-wave layout:
//   Uf2 flat idx = ((((lstm*16 + w)*8 + kt)*4 + g)*64 + l)*8 + e
//   = U[k = kt*32 + (l>>4)*8 + e][col = g*256 + w*16 + (l&15)]
// One block per (lstm, kt): stage 32 rows x 1024 cols in LDS, emit coalesced.
// ---------------------------------------------------------------------------
__global__ __launch_bounds__(256) void k_prep_u(
    const float* __restrict__ Uxp, const float* __restrict__ Uxn,
    const float* __restrict__ Uy, f16* __restrict__ Uf2)
{
  __shared__ f16 lds[32][1024];  // 64 KB
  const int tid = threadIdx.x;
  const int lstm = blockIdx.x >> 3, kt = blockIdx.x & 7;
  const float* src = (lstm < 32) ? (Uxp + (size_t)lstm * 262144)
                   : (lstm < 64) ? (Uxn + (size_t)(lstm - 32) * 262144)
                   : Uy;
  const int k0 = kt * 32;
  for (int i = tid; i < 32 * 1024; i += 256) {
    const int row = i >> 10, col = i & 1023;
    lds[row][col] = (f16)src[(size_t)(k0 + row) * 1024 + col];
  }
  __syncthreads();
  const int l = tid & 63, c0 = tid >> 6;
  for (int fc = c0; fc < 64; fc += 4) {
    const int w = fc >> 2, g = fc & 3;
    f16x8 v;
    #pragma unroll
    for (int e = 0; e < 8; ++e)
      v[e] = lds[(l >> 4) * 8 + e][g * 256 + w * 16 + (l & 15)];
    *(f16x8*)(Uf2 + (((((size_t)lstm * 16 + w) * 8 + kt) * 4 + g) * 64 + l) * 8) = v;
  }
}

// ---------------------------------------------------------------------------
// k_prep_wmi: pack all MI-LSTM recurrent weights into one f16 buffer.
// Column space c in [0,2304): 0-1023 Um, 1024-1535 Upa, 1536-2047 Una,
// 2048-2303 Wa.  Wmi[((kc*2304) + c)*8 + e] = W[k = kc*8+e][scol]
// ---------------------------------------------------------------------------
__global__ __launch_bounds__(64) void k_prep_wmi(
    const float* __restrict__ Um, const float* __restrict__ Upa,
    const float* __restrict__ Una, const float* __restrict__ Wa,
    f16* __restrict__ Wmi)
{
  const int l = threadIdx.x;
  const int c = blockIdx.x * 2 + (l >> 5);
  const int kc = l & 31;
  const float* src; int scol, ld;
  if (c < 1024)      { src = Um;  scol = c;        ld = 1024; }
  else if (c < 1536) { src = Upa; scol = c - 1024; ld = 512;  }
  else if (c < 2048) { src = Una; scol = c - 1536; ld = 512;  }
  else               { src = Wa;  scol = c - 2048; ld = 256;  }
  f16x8 v;
  #pragma unroll
  for (int e = 0; e < 8; ++e) v[e] = (f16)src[(size_t)(kc * 8 + e) * ld + scol];
  *(f16x8*)(Wmi + ((size_t)kc * 2304 + c) * 8) = v;
}

// ---------------------------------------------------------------------------
// k_prep_x: X[b][t][f] -> Xt[s][f][t][b]
// ---------------------------------------------------------------------------
__global__ __launch_bounds__(512) void k_prep_x(
    const float* __restrict__ Xp, const float* __restrict__ Xn, float* __restrict__ Xt)
{
  const int s = blockIdx.x >> 5, f = blockIdx.x & 31;
  const float* X = s ? Xn : Xp;
  for (int i = threadIdx.x; i < 2048; i += 512) {
    const int t = i >> 5, b = i & 31;
    Xt[((size_t)(s * 32 + f) * 64 + t) * 32 + b] = X[((size_t)b * 64 + t) * 32 + f];
  }
}

// ---------------------------------------------------------------------------
// k_prep_yg0: yg0t[t][col][b] = Y[b,t,:] @ Wy + by
// ---------------------------------------------------------------------------
__global__ __launch_bounds__(1024) void k_prep_yg0(
    const float* __restrict__ Y, const float* __restrict__ Wy,
    const float* __restrict__ by, float* __restrict__ yg0t)
{
  const int t = blockIdx.x, col = threadIdx.x;
  float wv[10];
  #pragma unroll
  for (int i = 0; i < 10; ++i) wv[i] = Wy[i * 1024 + col];
  const float bv = by[col];
  for (int b = 0; b < 32; ++b) {
    float a = bv;
    #pragma unroll
    for (int i = 0; i < 10; ++i) a += Y[((size_t)b * 64 + t) * 10 + i] * wv[i];
    yg0t[((size_t)t * 1024 + col) * 32 + b] = a;
  }
}

// ---------------------------------------------------------------------------
// k_scan v7: barrier-free streaming LSTM scan, 16 waves/block (spill-free).
// One block per LSTM (65 blocks, 1024 thr). Wave w owns n-tile w (16 cols,
// all 4 gates): Uc[4]/Un[4] + acc[4][2] = 64 VGPR of working set, fits 128.
// U streamed from L2 in fragment order every step (512 KB/step/block,
// 1-deep prefetch); h block-local in LDS frag layout (f16). Feature blocks
// write h to a private hseq slab; k_mean reduces afterwards.
// ---------------------------------------------------------------------------
__global__ __launch_bounds__(1024, 1) void k_scan(
    const float* __restrict__ Xt,
    const float* __restrict__ Wxp, const float* __restrict__ bxp,
    const float* __restrict__ Wxn, const float* __restrict__ bxn,
    const f16* __restrict__ Uf2, const float* __restrict__ yg0t,
    float* __restrict__ Yh, f16* __restrict__ hseq)
{
  __shared__ __align__(16) f16 hfrag[2 * 8 * 64 * 8];  // [mt][kt][lane][e], 16 KB
  const int tid = threadIdx.x;
  const int w = tid >> 6, l = tid & 63;
  const int cl = l & 15, lq = l >> 4;
  const int lstm = blockIdx.x;
  const bool isY = (lstm == 64);
  const int s = (lstm >= 32 && !isY) ? 1 : 0;
  const int f = lstm & 31;
  const int n = w * 16 + cl;                    // this thread's state column

  const f16* UB = Uf2 + ((size_t)(lstm * 16 + w) * 32) * 512 + (size_t)l * 8;

  float Wc[4], Bc[4];
  const float* xrow = nullptr;
  if (!isY) {
    const float* Wf = (s ? Wxn : Wxp) + (size_t)f * 1024;
    const float* bf = (s ? bxn : bxp) + (size_t)f * 1024;
    #pragma unroll
    for (int g = 0; g < 4; ++g) { Wc[g] = Wf[g * 256 + n]; Bc[g] = bf[g * 256 + n]; }
    xrow = Xt + (size_t)(s * 32 + f) * 2048;
  }
  f16* hout = hseq + (size_t)lstm * (64 * 32 * 256);

  float c[2][4];  // [mt][j]
  #pragma unroll
  for (int mt = 0; mt < 2; ++mt)
    #pragma unroll
    for (int j = 0; j < 4; ++j) c[mt][j] = 0.f;

  ((uint4*)hfrag)[tid] = uint4{0, 0, 0, 0};
  __syncthreads();

  // hfrag write coordinates for this thread's states (n fixed):
  const int wkt   = n >> 5;                     // dest kt slab
  const int lanehi = ((n >> 3) & 3) * 16;       // (w&1)*2 + (cl>>3) quarter
  const int we    = n & 7;

  for (int t = 0; t < T; ++t) {
    f32x4 acc[4][2];
    #pragma unroll
    for (int g = 0; g < 4; ++g) { acc[g][0] = f32x4{0,0,0,0}; acc[g][1] = f32x4{0,0,0,0}; }

    f16x8 Uc[4];
    #pragma unroll
    for (int g = 0; g < 4; ++g) Uc[g] = *(const f16x8*)(UB + g * 512);

    #pragma unroll
    for (int kt = 0; kt < 8; ++kt) {
      f16x8 Un[4];
      if (kt < 7) {
        #pragma unroll
        for (int g = 0; g < 4; ++g)
          Un[g] = *(const f16x8*)(UB + ((kt + 1) * 4 + g) * 512);
      }
      const f16x8 a0 = *(const f16x8*)(hfrag + (0 * 8 + kt) * 512 + l * 8);
      const f16x8 a1 = *(const f16x8*)(hfrag + (1 * 8 + kt) * 512 + l * 8);
      #pragma unroll
      for (int g = 0; g < 4; ++g) {
        acc[g][0] = __builtin_amdgcn_mfma_f32_16x16x32_f16(a0, Uc[g], acc[g][0], 0, 0, 0);
        acc[g][1] = __builtin_amdgcn_mfma_f32_16x16x32_f16(a1, Uc[g], acc[g][1], 0, 0, 0);
      }
      #pragma unroll
      for (int g = 0; g < 4; ++g) Uc[g] = Un[g];
    }
    __syncthreads();   // all waves done reading hfrag

    #pragma unroll
    for (int mt = 0; mt < 2; ++mt) {
      float4 xq;
      float4 yq[4];
      if (!isY) {
        xq = *(const float4*)(xrow + t * 32 + mt * 16 + lq * 4);
      } else {
        #pragma unroll
        for (int g = 0; g < 4; ++g)
          yq[g] = *(const float4*)(yg0t + ((size_t)t * 1024 + g * 256 + n) * 32 + mt * 16 + lq * 4);
      }
      #pragma unroll
      for (int j = 0; j < 4; ++j) {
        const int b = mt * 16 + lq * 4 + j;
        float p0, p1, p2, p3;
        if (isY) {
          p0 = acc[0][mt][j] + ((const float*)&yq[0])[j];
          p1 = acc[1][mt][j] + ((const float*)&yq[1])[j];
          p2 = acc[2][mt][j] + ((const float*)&yq[2])[j];
          p3 = acc[3][mt][j] + ((const float*)&yq[3])[j];
        } else {
          const float x = ((const float*)&xq)[j];
          p0 = acc[0][mt][j] + x * Wc[0] + Bc[0];
          p1 = acc[1][mt][j] + x * Wc[1] + Bc[1];
          p2 = acc[2][mt][j] + x * Wc[2] + Bc[2];
          p3 = acc[3][mt][j] + x * Wc[3] + Bc[3];
        }
        const float ig = sigm(p0), fg = sigm(p1), gy = ftanh(p2), og = sigm(p3);
        c[mt][j] = fg * c[mt][j] + ig * gy;
        const float h = og * ftanh(c[mt][j]);
        const int lanep = (lq * 4 + j) + lanehi;
        hfrag[(mt * 8 + wkt) * 512 + lanep * 8 + we] = (f16)h;
        if (isY) Yh[((size_t)b * T + t) * H + n] = h;
        else hout[(((size_t)t * 32 + b) * 256) + n] = (f16)h;
      }
    }
    __syncthreads();
  }
}

// ---------------------------------------------------------------------------
// k_mean: feature mean. Ph[(b*T+t)*H+n] = mean_f hseq[f][t][b][n] (f=0..31),
// Nh from f=32..63.
// ---------------------------------------------------------------------------
__global__ __launch_bounds__(256) void k_mean(
    const f16* __restrict__ hseq, float* __restrict__ Ph, float* __restrict__ Nh)
{
  const int bt = blockIdx.x;        // b*T + t
  const int b = bt >> 6, t = bt & 63;
  const int n = threadIdx.x;
  const size_t base = (((size_t)t * 32 + b) * 256) + n;
  float s0 = 0.f, s1 = 0.f;
  #pragma unroll
  for (int f = 0; f < 32; ++f) {
    s0 += (float)hseq[(size_t)f        * (64 * 32 * 256) + base];
    s1 += (float)hseq[(size_t)(f + 32) * (64 * 32 * 256) + base];
  }
  Ph[(size_t)bt * 256 + n] = s0 * 0.03125f;
  Nh[(size_t)bt * 256 + n] = s1 * 0.03125f;
}

// ---------------------------------------------------------------------------
// k_xg: MI-LSTM input projections.
// ---------------------------------------------------------------------------
__global__ __launch_bounds__(1024) void k_xg(
    const float* __restrict__ Yh, const float* __restrict__ Ph, const float* __restrict__ Nh,
    const float* __restrict__ Wm, const float* __restrict__ bm,
    const float* __restrict__ Wpa, const float* __restrict__ bpa,
    const float* __restrict__ Wna, const float* __restrict__ bna,
    float* __restrict__ yg, float* __restrict__ pg, float* __restrict__ ng)
{
  __shared__ __align__(16) float A[8][768];
  const int tid = threadIdx.x;
  const int ro  = blockIdx.x * 8;

  for (int idx = tid; idx < 8 * 768; idx += 1024) {
    const int r = idx / 768, cc = idx % 768;
    const int row = ro + r;
    float v;
    if (cc < 256)      v = Yh[(size_t)row * H + cc];
    else if (cc < 512) v = Ph[(size_t)row * H + (cc - 256)];
    else               v = Nh[(size_t)row * H + (cc - 512)];
    A[r][cc] = v;
  }
  __syncthreads();

  float acc[8];
  #pragma unroll
  for (int r = 0; r < 8; ++r) acc[r] = bm[tid];
  for (int k = 0; k < H; k += 4) {
    const float w0 = Wm[(k + 0) * 1024 + tid];
    const float w1 = Wm[(k + 1) * 1024 + tid];
    const float w2 = Wm[(k + 2) * 1024 + tid];
    const float w3 = Wm[(k + 3) * 1024 + tid];
    #pragma unroll
    for (int r = 0; r < 8; ++r) {
      const float4 av = *(const float4*)&A[r][k];
      acc[r] += w0 * av.x + w1 * av.y + w2 * av.z + w3 * av.w;
    }
  }
  #pragma unroll
  for (int r = 0; r < 8; ++r) yg[(size_t)(ro + r) * 1024 + tid] = acc[r];

  const int col = tid & 511;
  const float* Wx = (tid < 512) ? Wpa : Wna;
  const float* bx = (tid < 512) ? bpa : bna;
  float* outp     = (tid < 512) ? pg : ng;
  const int aoff  = (tid < 512) ? 256 : 512;
  #pragma unroll
  for (int r = 0; r < 8; ++r) acc[r] = bx[col];
  for (int k = 0; k < H; k += 4) {
    const float w0 = Wx[(k + 0) * 512 + col];
    const float w1 = Wx[(k + 1) * 512 + col];
    const float w2 = Wx[(k + 2) * 512 + col];
    const float w3 = Wx[(k + 3) * 512 + col];
    #pragma unroll
    for (int r = 0; r < 8; ++r) {
      const float4 av = *(const float4*)&A[r][aoff + k];
      acc[r] += w0 * av.x + w1 * av.y + w2 * av.z + w3 * av.w;
    }
  }
  #pragma unroll
  for (int r = 0; r < 8; ++r) outp[(size_t)(ro + r) * 512 + col] = acc[r];
}

// ---------------------------------------------------------------------------
// k_mi v5: one block per batch (32 blocks, 1024 thr), NO cross-block sync.
// Phase1 streams the packed 1.18 MB f16 weight buffer; phase2 does gates /
// cell-attention softmax / state update with in-block reductions.
// ---------------------------------------------------------------------------
__global__ __launch_bounds__(1024, 1) void k_mi(
    const float* __restrict__ yg, const float* __restrict__ pg, const float* __restrict__ ng,
    const f16* __restrict__ Wmi, const float* __restrict__ ba,
    float* __restrict__ Hm)
{
  __shared__ float g_all[2304];
  __shared__ __align__(16) f16 h_lds[256];
  __shared__ __align__(16) f16 c_lds[256];
  __shared__ float red[3][4];
  const int tid = threadIdx.x;
  const int b = blockIdx.x;

  if (tid < 256) { h_lds[tid] = (f16)0.f; c_lds[tid] = (f16)0.f; }
  const float bav = (tid < 256) ? ba[tid] : 0.f;
  float creg = 0.f;
  __syncthreads();

  for (int t = 0; t < T; ++t) {
    const size_t row = (size_t)b * T + t;

    float pre[8];
    if (tid < 256) {
      #pragma unroll
      for (int g = 0; g < 4; ++g) pre[g] = yg[row * 1024 + g * 256 + tid];
      pre[4] = pg[row * 512 + tid];       pre[5] = pg[row * 512 + 256 + tid];
      pre[6] = ng[row * 512 + tid];       pre[7] = ng[row * 512 + 256 + tid];
    }

    for (int c = tid; c < 2304; c += 1024) {
      const f16* hsrc = (c >= 2048) ? c_lds : h_lds;
      const f16* wcol = Wmi + (size_t)c * 8;
      float acc = 0.f;
      #pragma unroll 8
      for (int kc = 0; kc < 32; ++kc) {
        const f16x8 wv = *(const f16x8*)(wcol + (size_t)kc * 2304 * 8);
        const f16x8 hv = *(const f16x8*)(hsrc + kc * 8);
        #pragma unroll
        for (int e = 0; e < 8; ++e) acc += (float)wv[e] * (float)hv[e];
      }
      g_all[c] = acc;
    }
    __syncthreads();

    float l0 = 0.f, l1 = 0.f, l2 = 0.f, fg = 0.f, og = 0.f;
    if (tid < 256) {
      const int n = tid;
      const float gi = sigm(g_all[n]            + pre[0]);
      fg             = sigm(g_all[256 + n]      + pre[1]);
      const float gy = ftanh(g_all[512 + n]     + pre[2]);
      og             = sigm(g_all[768 + n]      + pre[3]);
      const float ip = sigm(g_all[1024 + n]     + pre[4]);
      const float cp = ftanh(g_all[1280 + n]    + pre[5]);
      const float in = sigm(g_all[1536 + n]     + pre[6]);
      const float cn = ftanh(g_all[1792 + n]    + pre[7]);
      const float att = ftanh(g_all[2048 + n]   + bav);
      l0 = gi * gy; l1 = ip * cp; l2 = in * cn;
      float v0 = l0 * att, v1 = l1 * att, v2 = l2 * att;
      #pragma unroll
      for (int off = 32; off; off >>= 1) {
        v0 += __shfl_down(v0, off);
        v1 += __shfl_down(v1, off);
        v2 += __shfl_down(v2, off);
      }
      if ((tid & 63) == 0) {
        red[0][tid >> 6] = v0; red[1][tid >> 6] = v1; red[2][tid >> 6] = v2;
      }
    }
    __syncthreads();

    if (tid < 256) {
      const int n = tid;
      const float s0 = red[0][0] + red[0][1] + red[0][2] + red[0][3];
      const float s1 = red[1][0] + red[1][1] + red[1][2] + red[1][3];
      const float s2 = red[2][0] + red[2][1] + red[2][2] + red[2][3];
      const float m  = fmaxf(s0, fmaxf(s1, s2));
      const float e0 = __expf(s0 - m), e1 = __expf(s1 - m), e2 = __expf(s2 - m);
      const float lt = (e0 * l0 + e1 * l1 + e2 * l2) / (e0 + e1 + e2);
      creg = fg * creg + lt;
      const float h = og * ftanh(creg);
      h_lds[n] = (f16)h;
      c_lds[n] = (f16)creg;
      Hm[row * H + n] = h;
    }
    __syncthreads();
  }
}

// ---------------------------------------------------------------------------
// k_att: temporal additive attention + linear head.
// ---------------------------------------------------------------------------
__global__ __launch_bounds__(256) void k_att(
    const float* __restrict__ Hm, const float* __restrict__ Watt, const float* __restrict__ batt,
    const float* __restrict__ vatt, const float* __restrict__ Wlin, const float* __restrict__ blin,
    float* __restrict__ out)
{
  __shared__ __align__(16) float hm8[8][H];
  __shared__ float vred[8][4];
  __shared__ float s_lds[T];
  __shared__ float alpha_lds[T];
  __shared__ float red4[4];
  const int n = threadIdx.x;
  const int b = blockIdx.x;
  const float bn = batt[n], vn = vatt[n];

  for (int t0 = 0; t0 < T; t0 += 8) {
    __syncthreads();
    #pragma unroll
    for (int r = 0; r < 8; ++r) hm8[r][n] = Hm[((size_t)b * T + t0 + r) * H + n];
    __syncthreads();
    float acc[8];
    #pragma unroll
    for (int r = 0; r < 8; ++r) acc[r] = bn;
    for (int k = 0; k < H; k += 4) {
      const float w0 = Watt[(k + 0) * H + n];
      const float w1 = Watt[(k + 1) * H + n];
      const float w2 = Watt[(k + 2) * H + n];
      const float w3 = Watt[(k + 3) * H + n];
      #pragma unroll
      for (int r = 0; r < 8; ++r) {
        const float4 hv = *(const float4*)&hm8[r][k];
        acc[r] += w0 * hv.x + w1 * hv.y + w2 * hv.z + w3 * hv.w;
      }
    }
    #pragma unroll
    for (int r = 0; r < 8; ++r) {
      float v = tanhf(acc[r]) * vn;
      for (int off = 32; off; off >>= 1) v += __shfl_down(v, off);
      if ((n & 63) == 0) vred[r][n >> 6] = v;
    }
    __syncthreads();
    if (n < 8) s_lds[t0 + n] = vred[n][0] + vred[n][1] + vred[n][2] + vred[n][3];
  }
  __syncthreads();

  if (n < T) {
    const float sv = s_lds[n];
    float m = sv;
    for (int off = 32; off; off >>= 1) m = fmaxf(m, __shfl_xor(m, off));
    const float e = expf(sv - m);
    float sum = e;
    for (int off = 32; off; off >>= 1) sum += __shfl_xor(sum, off);
    alpha_lds[n] = e / sum;
  }
  __syncthreads();

  float acc = 0.f;
  for (int t = 0; t < T; ++t) acc += alpha_lds[t] * Hm[((size_t)b * T + t) * H + n];
  float p = acc * Wlin[n];
  for (int off = 32; off; off >>= 1) p += __shfl_down(p, off);
  if ((n & 63) == 0) red4[n >> 6] = p;
  __syncthreads();
  if (n == 0) out[b] = fmaxf(red4[0] + red4[1] + red4[2] + red4[3] + blin[0], 0.f);
}

// ---------------------------------------------------------------------------
extern "C" void kernel_launch(void* const* d_in, const int* in_sizes, int n_in,
                              void* d_out, int out_size, void* d_ws, size_t ws_size,
                              hipStream_t stream) {
  const float* Yin  = (const float*)d_in[0];
  const float* Xp   = (const float*)d_in[1];
  const float* Xn   = (const float*)d_in[2];
  const float* Wy   = (const float*)d_in[3];
  const float* Uy   = (const float*)d_in[4];
  const float* by   = (const float*)d_in[5];
  const float* Wxp  = (const float*)d_in[6];
  const float* Uxp  = (const float*)d_in[7];
  const float* bxp  = (const float*)d_in[8];
  const float* Wxn  = (const float*)d_in[9];
  const float* Uxn  = (const float*)d_in[10];
  const float* bxn  = (const float*)d_in[11];
  const float* Wm   = (const float*)d_in[12];
  const float* Um   = (const float*)d_in[13];
  const float* bm   = (const float*)d_in[14];
  const float* Wpa  = (const float*)d_in[15];
  const float* Upa  = (const float*)d_in[16];
  const float* bpa  = (const float*)d_in[17];
  const float* Wna  = (const float*)d_in[18];
  const float* Una  = (const float*)d_in[19];
  const float* bna  = (const float*)d_in[20];
  const float* Wa   = (const float*)d_in[21];
  const float* ba   = (const float*)d_in[22];
  const float* Watt = (const float*)d_in[23];
  const float* batt = (const float*)d_in[24];
  const float* vatt = (const float*)d_in[25];
  const float* Wlin = (const float*)d_in[26];
  const float* blin = (const float*)d_in[27];

  float* ws = (float*)d_ws;
  float*    Yh    = ws;                         // 524288
  float*    Ph    = ws + 524288;                // 524288
  float*    Nh    = ws + 1048576;               // 524288
  float*    Hm    = ws + 1572864;               // 524288
  float*    yg    = ws + 2097152;               // 2097152
  float*    pg    = ws + 4194304;               // 1048576
  float*    ng    = ws + 5242880;               // 1048576
  float*    yg0t  = ws + 6291456;               // 2097152
  float*    Xt    = ws + 8388608;               // 131072
  f16*      Uf2   = (f16*)(ws + 8519680);       // 17039360 f16 (8519680 floats)
  f16*      Wmi   = (f16*)(ws + 17039360);      // 589824 f16 (294912 floats)
  f16*      hseq  = (f16*)(ws + 17334272);      // 64*64*32*256 f16 (16777216 floats)
  float*    out   = (float*)d_out;

  k_prep_u   <<<520, 256, 0, stream>>>(Uxp, Uxn, Uy, Uf2);
  k_prep_wmi <<<1152, 64, 0, stream>>>(Um, Upa, Una, Wa, Wmi);
  k_prep_x   <<<64, 512, 0, stream>>>(Xp, Xn, Xt);
  k_prep_yg0 <<<64, 1024, 0, stream>>>(Yin, Wy, by, yg0t);

  k_scan<<<65, 1024, 0, stream>>>(Xt, Wxp, bxp, Wxn, bxn, Uf2, yg0t, Yh, hseq);
  k_mean<<<2048, 256, 0, stream>>>(hseq, Ph, Nh);
  k_xg  <<<256, 1024, 0, stream>>>(Yh, Ph, Nh, Wm, bm, Wpa, bpa, Wna, bna, yg, pg, ng);
  k_mi  <<<32, 1024, 0, stream>>>(yg, pg, ng, Wmi, ba, Hm);
  k_att <<<32, 256, 0, stream>>>(Hm, Watt, batt, vatt, Wlin, blin, out);
}

// Round 8
// 2310.205 us; speedup vs baseline: 1.0275x; 1.0189x over previous
//
#include <hip/hip_runtime.h>
#include <math.h>

#define T 64
#define H 256

typedef _Float16 f16;
typedef _Float16 f16x8 __attribute__((ext_vector_type(8)));
typedef float f32x4 __attribute__((ext_vector_type(4)));

__device__ __forceinline__ float sigm(float x) { return 1.f / (1.f + __expf(-x)); }
__device__ __forceinline__ float ftanh(float x) { return 1.f - 2.f / (__expf(2.f * x) + 1.f); }

// ---------------------------------------------------------------------------
// k_prep_u: coalesced frag-ordering of the 65 scan-LSTM U matrices into f16,
// 16-wave layout:
//   Uf2 flat idx = ((((lstm*16 + w)*8 + kt)*4 + g)*64 + l)*8 + e
//   = U[k = kt*32 + (l>>4)*8 + e][col = g*256 + w*16 + (l&15)]
// ---------------------------------------------------------------------------
__global__ __launch_bounds__(256) void k_prep_u(
    const float* __restrict__ Uxp, const float* __restrict__ Uxn,
    const float* __restrict__ Uy, f16* __restrict__ Uf2)
{
  __shared__ f16 lds[32][1024];  // 64 KB
  const int tid = threadIdx.x;
  const int lstm = blockIdx.x >> 3, kt = blockIdx.x & 7;
  const float* src = (lstm < 32) ? (Uxp + (size_t)lstm * 262144)
                   : (lstm < 64) ? (Uxn + (size_t)(lstm - 32) * 262144)
                   : Uy;
  const int k0 = kt * 32;
  for (int i = tid; i < 32 * 1024; i += 256) {
    const int row = i >> 10, col = i & 1023;
    lds[row][col] = (f16)src[(size_t)(k0 + row) * 1024 + col];
  }
  __syncthreads();
  const int l = tid & 63, c0 = tid >> 6;
  for (int fc = c0; fc < 64; fc += 4) {
    const int w = fc >> 2, g = fc & 3;
    f16x8 v;
    #pragma unroll
    for (int e = 0; e < 8; ++e)
      v[e] = lds[(l >> 4) * 8 + e][g * 256 + w * 16 + (l & 15)];
    *(f16x8*)(Uf2 + (((((size_t)lstm * 16 + w) * 8 + kt) * 4 + g) * 64 + l) * 8) = v;
  }
}

// ---------------------------------------------------------------------------
// k_prep_wmi: pack all MI-LSTM recurrent weights into one f16 buffer.
// Column space c in [0,2304): 0-1023 Um, 1024-1535 Upa, 1536-2047 Una,
// 2048-2303 Wa.  Wmi[((kc*2304) + c)*8 + e] = W[k = kc*8+e][scol]
// ---------------------------------------------------------------------------
__global__ __launch_bounds__(64) void k_prep_wmi(
    const float* __restrict__ Um, const float* __restrict__ Upa,
    const float* __restrict__ Una, const float* __restrict__ Wa,
    f16* __restrict__ Wmi)
{
  const int l = threadIdx.x;
  const int c = blockIdx.x * 2 + (l >> 5);
  const int kc = l & 31;
  const float* src; int scol, ld;
  if (c < 1024)      { src = Um;  scol = c;        ld = 1024; }
  else if (c < 1536) { src = Upa; scol = c - 1024; ld = 512;  }
  else if (c < 2048) { src = Una; scol = c - 1536; ld = 512;  }
  else               { src = Wa;  scol = c - 2048; ld = 256;  }
  f16x8 v;
  #pragma unroll
  for (int e = 0; e < 8; ++e) v[e] = (f16)src[(size_t)(kc * 8 + e) * ld + scol];
  *(f16x8*)(Wmi + ((size_t)kc * 2304 + c) * 8) = v;
}

// ---------------------------------------------------------------------------
// k_prep_x: X[b][t][f] -> Xt[s][f][t][b]
// ---------------------------------------------------------------------------
__global__ __launch_bounds__(512) void k_prep_x(
    const float* __restrict__ Xp, const float* __restrict__ Xn, float* __restrict__ Xt)
{
  const int s = blockIdx.x >> 5, f = blockIdx.x & 31;
  const float* X = s ? Xn : Xp;
  for (int i = threadIdx.x; i < 2048; i += 512) {
    const int t = i >> 5, b = i & 31;
    Xt[((size_t)(s * 32 + f) * 64 + t) * 32 + b] = X[((size_t)b * 64 + t) * 32 + f];
  }
}

// ---------------------------------------------------------------------------
// k_prep_yg0: yg0t[t][col][b] = Y[b,t,:] @ Wy + by
// ---------------------------------------------------------------------------
__global__ __launch_bounds__(1024) void k_prep_yg0(
    const float* __restrict__ Y, const float* __restrict__ Wy,
    const float* __restrict__ by, float* __restrict__ yg0t)
{
  const int t = blockIdx.x, col = threadIdx.x;
  float wv[10];
  #pragma unroll
  for (int i = 0; i < 10; ++i) wv[i] = Wy[i * 1024 + col];
  const float bv = by[col];
  for (int b = 0; b < 32; ++b) {
    float a = bv;
    #pragma unroll
    for (int i = 0; i < 10; ++i) a += Y[((size_t)b * 64 + t) * 10 + i] * wv[i];
    yg0t[((size_t)t * 1024 + col) * 32 + b] = a;
  }
}

// ---------------------------------------------------------------------------
// k_scan v8: barrier-light streaming LSTM scan, 16 waves/block.
// One block per LSTM (65 blocks, 1024 thr). Wave w owns n-tile w (16 cols,
// all 4 gates). U streamed via 3-group-deep rotating prefetch B[3][4]
// (12 loads in flight ~1200cy cover > ~900cy L3 miss latency; kt-loop fully
// unrolled so all B indices are static). hfrag double-buffered -> ONE
// __syncthreads (one vmcnt drain) per step.
// ---------------------------------------------------------------------------
__global__ __launch_bounds__(1024, 1) void k_scan(
    const float* __restrict__ Xt,
    const float* __restrict__ Wxp, const float* __restrict__ bxp,
    const float* __restrict__ Wxn, const float* __restrict__ bxn,
    const f16* __restrict__ Uf2, const float* __restrict__ yg0t,
    float* __restrict__ Yh, f16* __restrict__ hseq)
{
  __shared__ __align__(16) f16 hfrag[2][2 * 8 * 64 * 8];  // [buf][mt*8+kt][lane][e], 2x16KB
  const int tid = threadIdx.x;
  const int w = tid >> 6, l = tid & 63;
  const int cl = l & 15, lq = l >> 4;
  const int lstm = blockIdx.x;
  const bool isY = (lstm == 64);
  const int s = (lstm >= 32 && !isY) ? 1 : 0;
  const int f = lstm & 31;
  const int n = w * 16 + cl;                    // this thread's state column

  const f16* UB = Uf2 + ((size_t)(lstm * 16 + w) * 32) * 512 + (size_t)l * 8;

  float Wc[4], Bc[4];
  const float* xrow = nullptr;
  if (!isY) {
    const float* Wf = (s ? Wxn : Wxp) + (size_t)f * 1024;
    const float* bf = (s ? bxn : bxp) + (size_t)f * 1024;
    #pragma unroll
    for (int g = 0; g < 4; ++g) { Wc[g] = Wf[g * 256 + n]; Bc[g] = bf[g * 256 + n]; }
    xrow = Xt + (size_t)(s * 32 + f) * 2048;
  }
  f16* hout = hseq + (size_t)lstm * (64 * 32 * 256);

  float c[2][4];  // [mt][j]
  #pragma unroll
  for (int mt = 0; mt < 2; ++mt)
    #pragma unroll
    for (int j = 0; j < 4; ++j) c[mt][j] = 0.f;

  ((uint4*)&hfrag[0][0])[tid] = uint4{0, 0, 0, 0};  // zero buf 0 (16 KB)
  __syncthreads();

  // hfrag write coordinates for this thread's states (n fixed):
  const int wkt    = n >> 5;                    // dest kt slab
  const int lanehi = ((n >> 3) & 3) * 16;
  const int we     = n & 7;

  for (int t = 0; t < T; ++t) {
    const f16* hb = hfrag[t & 1];
    f16*       hw = hfrag[(t + 1) & 1];

    // prologue: issue prefetch groups 0..2 (slots 0..2)
    f16x8 B[3][4];
    #pragma unroll
    for (int sl = 0; sl < 3; ++sl)
      #pragma unroll
      for (int g = 0; g < 4; ++g)
        B[sl][g] = *(const f16x8*)(UB + (sl * 4 + g) * 512);

    f32x4 acc[4][2];
    #pragma unroll
    for (int g = 0; g < 4; ++g) { acc[g][0] = f32x4{0,0,0,0}; acc[g][1] = f32x4{0,0,0,0}; }

    #pragma unroll
    for (int kt = 0; kt < 8; ++kt) {
      const f16x8 a0 = *(const f16x8*)(hb + (0 * 8 + kt) * 512 + l * 8);
      const f16x8 a1 = *(const f16x8*)(hb + (1 * 8 + kt) * 512 + l * 8);
      #pragma unroll
      for (int g = 0; g < 4; ++g) {
        acc[g][0] = __builtin_amdgcn_mfma_f32_16x16x32_f16(a0, B[kt % 3][g], acc[g][0], 0, 0, 0);
        acc[g][1] = __builtin_amdgcn_mfma_f32_16x16x32_f16(a1, B[kt % 3][g], acc[g][1], 0, 0, 0);
      }
      if (kt < 5) {   // refill just-freed slot with group kt+3
        #pragma unroll
        for (int g = 0; g < 4; ++g)
          B[kt % 3][g] = *(const f16x8*)(UB + ((kt + 3) * 4 + g) * 512);
      }
    }

    // epilogue (no barrier needed: writes go to the other hfrag buffer)
    #pragma unroll
    for (int mt = 0; mt < 2; ++mt) {
      float4 xq;
      float4 yq[4];
      if (!isY) {
        xq = *(const float4*)(xrow + t * 32 + mt * 16 + lq * 4);
      } else {
        #pragma unroll
        for (int g = 0; g < 4; ++g)
          yq[g] = *(const float4*)(yg0t + ((size_t)t * 1024 + g * 256 + n) * 32 + mt * 16 + lq * 4);
      }
      #pragma unroll
      for (int j = 0; j < 4; ++j) {
        const int b = mt * 16 + lq * 4 + j;
        float p0, p1, p2, p3;
        if (isY) {
          p0 = acc[0][mt][j] + ((const float*)&yq[0])[j];
          p1 = acc[1][mt][j] + ((const float*)&yq[1])[j];
          p2 = acc[2][mt][j] + ((const float*)&yq[2])[j];
          p3 = acc[3][mt][j] + ((const float*)&yq[3])[j];
        } else {
          const float x = ((const float*)&xq)[j];
          p0 = acc[0][mt][j] + x * Wc[0] + Bc[0];
          p1 = acc[1][mt][j] + x * Wc[1] + Bc[1];
          p2 = acc[2][mt][j] + x * Wc[2] + Bc[2];
          p3 = acc[3][mt][j] + x * Wc[3] + Bc[3];
        }
        const float ig = sigm(p0), fg = sigm(p1), gy = ftanh(p2), og = sigm(p3);
        c[mt][j] = fg * c[mt][j] + ig * gy;
        const float h = og * ftanh(c[mt][j]);
        const int lanep = (lq * 4 + j) + lanehi;
        hw[(mt * 8 + wkt) * 512 + lanep * 8 + we] = (f16)h;
        if (isY) Yh[((size_t)b * T + t) * H + n] = h;
        else hout[(((size_t)t * 32 + b) * 256) + n] = (f16)h;
      }
    }
    __syncthreads();   // single barrier: hw visible for next step's reads
  }
}

// ---------------------------------------------------------------------------
// k_mean: feature mean. Ph[(b*T+t)*H+n] = mean_f hseq[f][t][b][n] (f=0..31),
// Nh from f=32..63.
// ---------------------------------------------------------------------------
__global__ __launch_bounds__(256) void k_mean(
    const f16* __restrict__ hseq, float* __restrict__ Ph, float* __restrict__ Nh)
{
  const int bt = blockIdx.x;        // b*T + t
  const int b = bt >> 6, t = bt & 63;
  const int n = threadIdx.x;
  const size_t base = (((size_t)t * 32 + b) * 256) + n;
  float s0 = 0.f, s1 = 0.f;
  #pragma unroll
  for (int f = 0; f < 32; ++f) {
    s0 += (float)hseq[(size_t)f        * (64 * 32 * 256) + base];
    s1 += (float)hseq[(size_t)(f + 32) * (64 * 32 * 256) + base];
  }
  Ph[(size_t)bt * 256 + n] = s0 * 0.03125f;
  Nh[(size_t)bt * 256 + n] = s1 * 0.03125f;
}

// ---------------------------------------------------------------------------
// k_xg: MI-LSTM input projections.
// ---------------------------------------------------------------------------
__global__ __launch_bounds__(1024) void k_xg(
    const float* __restrict__ Yh, const float* __restrict__ Ph, const float* __restrict__ Nh,
    const float* __restrict__ Wm, const float* __restrict__ bm,
    const float* __restrict__ Wpa, const float* __restrict__ bpa,
    const float* __restrict__ Wna, const float* __restrict__ bna,
    float* __restrict__ yg, float* __restrict__ pg, float* __restrict__ ng)
{
  __shared__ __align__(16) float A[8][768];
  const int tid = threadIdx.x;
  const int ro  = blockIdx.x * 8;

  for (int idx = tid; idx < 8 * 768; idx += 1024) {
    const int r = idx / 768, cc = idx % 768;
    const int row = ro + r;
    float v;
    if (cc < 256)      v = Yh[(size_t)row * H + cc];
    else if (cc < 512) v = Ph[(size_t)row * H + (cc - 256)];
    else               v = Nh[(size_t)row * H + (cc - 512)];
    A[r][cc] = v;
  }
  __syncthreads();

  float acc[8];
  #pragma unroll
  for (int r = 0; r < 8; ++r) acc[r] = bm[tid];
  for (int k = 0; k < H; k += 4) {
    const float w0 = Wm[(k + 0) * 1024 + tid];
    const float w1 = Wm[(k + 1) * 1024 + tid];
    const float w2 = Wm[(k + 2) * 1024 + tid];
    const float w3 = Wm[(k + 3) * 1024 + tid];
    #pragma unroll
    for (int r = 0; r < 8; ++r) {
      const float4 av = *(const float4*)&A[r][k];
      acc[r] += w0 * av.x + w1 * av.y + w2 * av.z + w3 * av.w;
    }
  }
  #pragma unroll
  for (int r = 0; r < 8; ++r) yg[(size_t)(ro + r) * 1024 + tid] = acc[r];

  const int col = tid & 511;
  const float* Wx = (tid < 512) ? Wpa : Wna;
  const float* bx = (tid < 512) ? bpa : bna;
  float* outp     = (tid < 512) ? pg : ng;
  const int aoff  = (tid < 512) ? 256 : 512;
  #pragma unroll
  for (int r = 0; r < 8; ++r) acc[r] = bx[col];
  for (int k = 0; k < H; k += 4) {
    const float w0 = Wx[(k + 0) * 512 + col];
    const float w1 = Wx[(k + 1) * 512 + col];
    const float w2 = Wx[(k + 2) * 512 + col];
    const float w3 = Wx[(k + 3) * 512 + col];
    #pragma unroll
    for (int r = 0; r < 8; ++r) {
      const float4 av = *(const float4*)&A[r][aoff + k];
      acc[r] += w0 * av.x + w1 * av.y + w2 * av.z + w3 * av.w;
    }
  }
  #pragma unroll
  for (int r = 0; r < 8; ++r) outp[(size_t)(ro + r) * 512 + col] = acc[r];
}

// ---------------------------------------------------------------------------
// k_mi v5: one block per batch (32 blocks, 1024 thr), NO cross-block sync.
// Phase1 streams the packed 1.18 MB f16 weight buffer; phase2 does gates /
// cell-attention softmax / state update with in-block reductions.
// ---------------------------------------------------------------------------
__global__ __launch_bounds__(1024, 1) void k_mi(
    const float* __restrict__ yg, const float* __restrict__ pg, const float* __restrict__ ng,
    const f16* __restrict__ Wmi, const float* __restrict__ ba,
    float* __restrict__ Hm)
{
  __shared__ float g_all[2304];
  __shared__ __align__(16) f16 h_lds[256];
  __shared__ __align__(16) f16 c_lds[256];
  __shared__ float red[3][4];
  const int tid = threadIdx.x;
  const int b = blockIdx.x;

  if (tid < 256) { h_lds[tid] = (f16)0.f; c_lds[tid] = (f16)0.f; }
  const float bav = (tid < 256) ? ba[tid] : 0.f;
  float creg = 0.f;
  __syncthreads();

  for (int t = 0; t < T; ++t) {
    const size_t row = (size_t)b * T + t;

    float pre[8];
    if (tid < 256) {
      #pragma unroll
      for (int g = 0; g < 4; ++g) pre[g] = yg[row * 1024 + g * 256 + tid];
      pre[4] = pg[row * 512 + tid];       pre[5] = pg[row * 512 + 256 + tid];
      pre[6] = ng[row * 512 + tid];       pre[7] = ng[row * 512 + 256 + tid];
    }

    for (int c = tid; c < 2304; c += 1024) {
      const f16* hsrc = (c >= 2048) ? c_lds : h_lds;
      const f16* wcol = Wmi + (size_t)c * 8;
      float acc = 0.f;
      #pragma unroll 8
      for (int kc = 0; kc < 32; ++kc) {
        const f16x8 wv = *(const f16x8*)(wcol + (size_t)kc * 2304 * 8);
        const f16x8 hv = *(const f16x8*)(hsrc + kc * 8);
        #pragma unroll
        for (int e = 0; e < 8; ++e) acc += (float)wv[e] * (float)hv[e];
      }
      g_all[c] = acc;
    }
    __syncthreads();

    float l0 = 0.f, l1 = 0.f, l2 = 0.f, fg = 0.f, og = 0.f;
    if (tid < 256) {
      const int n = tid;
      const float gi = sigm(g_all[n]            + pre[0]);
      fg             = sigm(g_all[256 + n]      + pre[1]);
      const float gy = ftanh(g_all[512 + n]     + pre[2]);
      og             = sigm(g_all[768 + n]      + pre[3]);
      const float ip = sigm(g_all[1024 + n]     + pre[4]);
      const float cp = ftanh(g_all[1280 + n]    + pre[5]);
      const float in = sigm(g_all[1536 + n]     + pre[6]);
      const float cn = ftanh(g_all[1792 + n]    + pre[7]);
      const float att = ftanh(g_all[2048 + n]   + bav);
      l0 = gi * gy; l1 = ip * cp; l2 = in * cn;
      float v0 = l0 * att, v1 = l1 * att, v2 = l2 * att;
      #pragma unroll
      for (int off = 32; off; off >>= 1) {
        v0 += __shfl_down(v0, off);
        v1 += __shfl_down(v1, off);
        v2 += __shfl_down(v2, off);
      }
      if ((tid & 63) == 0) {
        red[0][tid >> 6] = v0; red[1][tid >> 6] = v1; red[2][tid >> 6] = v2;
      }
    }
    __syncthreads();

    if (tid < 256) {
      const int n = tid;
      const float s0 = red[0][0] + red[0][1] + red[0][2] + red[0][3];
      const float s1 = red[1][0] + red[1][1] + red[1][2] + red[1][3];
      const float s2 = red[2][0] + red[2][1] + red[2][2] + red[2][3];
      const float m  = fmaxf(s0, fmaxf(s1, s2));
      const float e0 = __expf(s0 - m), e1 = __expf(s1 - m), e2 = __expf(s2 - m);
      const float lt = (e0 * l0 + e1 * l1 + e2 * l2) / (e0 + e1 + e2);
      creg = fg * creg + lt;
      const float h = og * ftanh(creg);
      h_lds[n] = (f16)h;
      c_lds[n] = (f16)creg;
      Hm[row * H + n] = h;
    }
    __syncthreads();
  }
}

// ---------------------------------------------------------------------------
// k_att: temporal additive attention + linear head.
// ---------------------------------------------------------------------------
__global__ __launch_bounds__(256) void k_att(
    const float* __restrict__ Hm, const float* __restrict__ Watt, const float* __restrict__ batt,
    const float* __restrict__ vatt, const float* __restrict__ Wlin, const float* __restrict__ blin,
    float* __restrict__ out)
{
  __shared__ __align__(16) float hm8[8][H];
  __shared__ float vred[8][4];
  __shared__ float s_lds[T];
  __shared__ float alpha_lds[T];
  __shared__ float red4[4];
  const int n = threadIdx.x;
  const int b = blockIdx.x;
  const float bn = batt[n], vn = vatt[n];

  for (int t0 = 0; t0 < T; t0 += 8) {
    __syncthreads();
    #pragma unroll
    for (int r = 0; r < 8; ++r) hm8[r][n] = Hm[((size_t)b * T + t0 + r) * H + n];
    __syncthreads();
    float acc[8];
    #pragma unroll
    for (int r = 0; r < 8; ++r) acc[r] = bn;
    for (int k = 0; k < H; k += 4) {
      const float w0 = Watt[(k + 0) * H + n];
      const float w1 = Watt[(k + 1) * H + n];
      const float w2 = Watt[(k + 2) * H + n];
      const float w3 = Watt[(k + 3) * H + n];
      #pragma unroll
      for (int r = 0; r < 8; ++r) {
        const float4 hv = *(const float4*)&hm8[r][k];
        acc[r] += w0 * hv.x + w1 * hv.y + w2 * hv.z + w3 * hv.w;
      }
    }
    #pragma unroll
    for (int r = 0; r < 8; ++r) {
      float v = tanhf(acc[r]) * vn;
      for (int off = 32; off; off >>= 1) v += __shfl_down(v, off);
      if ((n & 63) == 0) vred[r][n >> 6] = v;
    }
    __syncthreads();
    if (n < 8) s_lds[t0 + n] = vred[n][0] + vred[n][1] + vred[n][2] + vred[n][3];
  }
  __syncthreads();

  if (n < T) {
    const float sv = s_lds[n];
    float m = sv;
    for (int off = 32; off; off >>= 1) m = fmaxf(m, __shfl_xor(m, off));
    const float e = expf(sv - m);
    float sum = e;
    for (int off = 32; off; off >>= 1) sum += __shfl_xor(sum, off);
    alpha_lds[n] = e / sum;
  }
  __syncthreads();

  float acc = 0.f;
  for (int t = 0; t < T; ++t) acc += alpha_lds[t] * Hm[((size_t)b * T + t) * H + n];
  float p = acc * Wlin[n];
  for (int off = 32; off; off >>= 1) p += __shfl_down(p, off);
  if ((n & 63) == 0) red4[n >> 6] = p;
  __syncthreads();
  if (n == 0) out[b] = fmaxf(red4[0] + red4[1] + red4[2] + red4[3] + blin[0], 0.f);
}

// ---------------------------------------------------------------------------
extern "C" void kernel_launch(void* const* d_in, const int* in_sizes, int n_in,
                              void* d_out, int out_size, void* d_ws, size_t ws_size,
                              hipStream_t stream) {
  const float* Yin  = (const float*)d_in[0];
  const float* Xp   = (const float*)d_in[1];
  const float* Xn   = (const float*)d_in[2];
  const float* Wy   = (const float*)d_in[3];
  const float* Uy   = (const float*)d_in[4];
  const float* by   = (const float*)d_in[5];
  const float* Wxp  = (const float*)d_in[6];
  const float* Uxp  = (const float*)d_in[7];
  const float* bxp  = (const float*)d_in[8];
  const float* Wxn  = (const float*)d_in[9];
  const float* Uxn  = (const float*)d_in[10];
  const float* bxn  = (const float*)d_in[11];
  const float* Wm   = (const float*)d_in[12];
  const float* Um   = (const float*)d_in[13];
  const float* bm   = (const float*)d_in[14];
  const float* Wpa  = (const float*)d_in[15];
  const float* Upa  = (const float*)d_in[16];
  const float* bpa  = (const float*)d_in[17];
  const float* Wna  = (const float*)d_in[18];
  const float* Una  = (const float*)d_in[19];
  const float* bna  = (const float*)d_in[20];
  const float* Wa   = (const float*)d_in[21];
  const float* ba   = (const float*)d_in[22];
  const float* Watt = (const float*)d_in[23];
  const float* batt = (const float*)d_in[24];
  const float* vatt = (const float*)d_in[25];
  const float* Wlin = (const float*)d_in[26];
  const float* blin = (const float*)d_in[27];

  float* ws = (float*)d_ws;
  float*    Yh    = ws;                         // 524288
  float*    Ph    = ws + 524288;                // 524288
  float*    Nh    = ws + 1048576;               // 524288
  float*    Hm    = ws + 1572864;               // 524288
  float*    yg    = ws + 2097152;               // 2097152
  float*    pg    = ws + 4194304;               // 1048576
  float*    ng    = ws + 5242880;               // 1048576
  float*    yg0t  = ws + 6291456;               // 2097152
  float*    Xt    = ws + 8388608;               // 131072
  f16*      Uf2   = (f16*)(ws + 8519680);       // 17039360 f16 (8519680 floats)
  f16*      Wmi   = (f16*)(ws + 17039360);      // 589824 f16 (294912 floats)
  f16*      hseq  = (f16*)(ws + 17334272);      // 64*64*32*256 f16 (16777216 floats)
  float*    out   = (float*)d_out;

  k_prep_u   <<<520, 256, 0, stream>>>(Uxp, Uxn, Uy, Uf2);
  k_prep_wmi <<<1152, 64, 0, stream>>>(Um, Upa, Una, Wa, Wmi);
  k_prep_x   <<<64, 512, 0, stream>>>(Xp, Xn, Xt);
  k_prep_yg0 <<<64, 1024, 0, stream>>>(Yin, Wy, by, yg0t);

  k_scan<<<65, 1024, 0, stream>>>(Xt, Wxp, bxp, Wxn, bxn, Uf2, yg0t, Yh, hseq);
  k_mean<<<2048, 256, 0, stream>>>(hseq, Ph, Nh);
  k_xg  <<<256, 1024, 0, stream>>>(Yh, Ph, Nh, Wm, bm, Wpa, bpa, Wna, bna, yg, pg, ng);
  k_mi  <<<32, 1024, 0, stream>>>(yg, pg, ng, Wmi, ba, Hm);
  k_att <<<32, 256, 0, stream>>>(Hm, Watt, batt, vatt, Wlin, blin, out);
}

// Round 9
// 2260.148 us; speedup vs baseline: 1.0503x; 1.0221x over previous
//
#include <hip/hip_runtime.h>
#include <math.h>

#define T 64
#define H 256

typedef _Float16 f16;
typedef _Float16 f16x8 __attribute__((ext_vector_type(8)));
typedef float f32x4 __attribute__((ext_vector_type(4)));

typedef const __attribute__((address_space(1))) void gas_void;
typedef __attribute__((address_space(3))) void las_void;

__device__ __forceinline__ float sigm(float x) { return 1.f / (1.f + __expf(-x)); }
__device__ __forceinline__ float ftanh(float x) { return 1.f - 2.f / (__expf(2.f * x) + 1.f); }

// async global->LDS DMA, 16 B per lane. lds dest = base + lane*16 (HW rule);
// global src is per-lane.
__device__ __forceinline__ void gload_lds16(const void* g, void* l) {
  __builtin_amdgcn_global_load_lds((gas_void*)g, (las_void*)l, 16, 0, 0);
}

// ---------------------------------------------------------------------------
// k_prep_u: coalesced frag-ordering of the 65 scan-LSTM U matrices into f16,
// 16-wave layout:
//   Uf2 flat idx = ((((lstm*16 + w)*8 + kt)*4 + g)*64 + l)*8 + e
//   = U[k = kt*32 + (l>>4)*8 + e][col = g*256 + w*16 + (l&15)]
// chunk (kt,g) is a contiguous 1 KB lane-ordered block -> global_load_lds-able.
// ---------------------------------------------------------------------------
__global__ __launch_bounds__(256) void k_prep_u(
    const float* __restrict__ Uxp, const float* __restrict__ Uxn,
    const float* __restrict__ Uy, f16* __restrict__ Uf2)
{
  __shared__ f16 lds[32][1024];  // 64 KB
  const int tid = threadIdx.x;
  const int lstm = blockIdx.x >> 3, kt = blockIdx.x & 7;
  const float* src = (lstm < 32) ? (Uxp + (size_t)lstm * 262144)
                   : (lstm < 64) ? (Uxn + (size_t)(lstm - 32) * 262144)
                   : Uy;
  const int k0 = kt * 32;
  for (int i = tid; i < 32 * 1024; i += 256) {
    const int row = i >> 10, col = i & 1023;
    lds[row][col] = (f16)src[(size_t)(k0 + row) * 1024 + col];
  }
  __syncthreads();
  const int l = tid & 63, c0 = tid >> 6;
  for (int fc = c0; fc < 64; fc += 4) {
    const int w = fc >> 2, g = fc & 3;
    f16x8 v;
    #pragma unroll
    for (int e = 0; e < 8; ++e)
      v[e] = lds[(l >> 4) * 8 + e][g * 256 + w * 16 + (l & 15)];
    *(f16x8*)(Uf2 + (((((size_t)lstm * 16 + w) * 8 + kt) * 4 + g) * 64 + l) * 8) = v;
  }
}

// ---------------------------------------------------------------------------
// k_prep_wmi: pack all MI-LSTM recurrent weights into one f16 buffer.
// ---------------------------------------------------------------------------
__global__ __launch_bounds__(64) void k_prep_wmi(
    const float* __restrict__ Um, const float* __restrict__ Upa,
    const float* __restrict__ Una, const float* __restrict__ Wa,
    f16* __restrict__ Wmi)
{
  const int l = threadIdx.x;
  const int c = blockIdx.x * 2 + (l >> 5);
  const int kc = l & 31;
  const float* src; int scol, ld;
  if (c < 1024)      { src = Um;  scol = c;        ld = 1024; }
  else if (c < 1536) { src = Upa; scol = c - 1024; ld = 512;  }
  else if (c < 2048) { src = Una; scol = c - 1536; ld = 512;  }
  else               { src = Wa;  scol = c - 2048; ld = 256;  }
  f16x8 v;
  #pragma unroll
  for (int e = 0; e < 8; ++e) v[e] = (f16)src[(size_t)(kc * 8 + e) * ld + scol];
  *(f16x8*)(Wmi + ((size_t)kc * 2304 + c) * 8) = v;
}

// ---------------------------------------------------------------------------
// k_prep_x: X[b][t][f] -> Xt[s][f][t][b]
// ---------------------------------------------------------------------------
__global__ __launch_bounds__(512) void k_prep_x(
    const float* __restrict__ Xp, const float* __restrict__ Xn, float* __restrict__ Xt)
{
  const int s = blockIdx.x >> 5, f = blockIdx.x & 31;
  const float* X = s ? Xn : Xp;
  for (int i = threadIdx.x; i < 2048; i += 512) {
    const int t = i >> 5, b = i & 31;
    Xt[((size_t)(s * 32 + f) * 64 + t) * 32 + b] = X[((size_t)b * 64 + t) * 32 + f];
  }
}

// ---------------------------------------------------------------------------
// k_prep_yg0: yg0t[t][col][b] = Y[b,t,:] @ Wy + by
// ---------------------------------------------------------------------------
__global__ __launch_bounds__(1024) void k_prep_yg0(
    const float* __restrict__ Y, const float* __restrict__ Wy,
    const float* __restrict__ by, float* __restrict__ yg0t)
{
  const int t = blockIdx.x, col = threadIdx.x;
  float wv[10];
  #pragma unroll
  for (int i = 0; i < 10; ++i) wv[i] = Wy[i * 1024 + col];
  const float bv = by[col];
  for (int b = 0; b < 32; ++b) {
    float a = bv;
    #pragma unroll
    for (int i = 0; i < 10; ++i) a += Y[((size_t)b * 64 + t) * 10 + i] * wv[i];
    yg0t[((size_t)t * 1024 + col) * 32 + b] = a;
  }
}

// ---------------------------------------------------------------------------
// k_scan v10: DMA-staged streaming LSTM scan. One block per LSTM (65 blocks,
// 1024 thr = 16 waves). Wave w owns n-tile w (16 cols x 4 gates). U is staged
// via global_load_lds into a per-wave 3-slot ring of 1 KB chunks (48 KB LDS),
// consumed with counted s_waitcnt vmcnt(2) (never 0 mid-loop). Queue depth is
// decoupled from VGPRs -> ~48 KB in flight per CU vs ~1 KB before.
// hfrag: single 16 KB buffer, 2 barriers/step.
// ---------------------------------------------------------------------------
__global__ __launch_bounds__(1024, 1) void k_scan(
    const float* __restrict__ Xt,
    const float* __restrict__ Wxp, const float* __restrict__ bxp,
    const float* __restrict__ Wxn, const float* __restrict__ bxn,
    const f16* __restrict__ Uf2, const float* __restrict__ yg0t,
    float* __restrict__ Yh, f16* __restrict__ hseq)
{
  __shared__ __align__(16) f16 hfrag[2 * 8 * 64 * 8];   // 16 KB
  __shared__ __align__(16) f16 uring[16][3][512];       // 48 KB
  const int tid = threadIdx.x;
  const int w = tid >> 6, l = tid & 63;
  const int cl = l & 15, lq = l >> 4;
  const int lstm = blockIdx.x;
  const bool isY = (lstm == 64);
  const int s = (lstm >= 32 && !isY) ? 1 : 0;
  const int f = lstm & 31;
  const int n = w * 16 + cl;                    // this thread's state column

  // per-lane global src base (chunk c at +c*512 f16)
  const f16* UB = Uf2 + ((size_t)(lstm * 16 + w) * 32) * 512 + (size_t)l * 8;
  f16* ring = &uring[w][0][0];                  // wave-uniform LDS base

  float Wc[4], Bc[4];
  const float* xrow = nullptr;
  if (!isY) {
    const float* Wf = (s ? Wxn : Wxp) + (size_t)f * 1024;
    const float* bf = (s ? bxn : bxp) + (size_t)f * 1024;
    #pragma unroll
    for (int g = 0; g < 4; ++g) { Wc[g] = Wf[g * 256 + n]; Bc[g] = bf[g * 256 + n]; }
    xrow = Xt + (size_t)(s * 32 + f) * 2048;
  }
  f16* hout = hseq + (size_t)lstm * (64 * 32 * 256);

  float c2[2][4];  // [mt][j]
  #pragma unroll
  for (int mt = 0; mt < 2; ++mt)
    #pragma unroll
    for (int j = 0; j < 4; ++j) c2[mt][j] = 0.f;

  ((uint4*)hfrag)[tid] = uint4{0, 0, 0, 0};     // zero hfrag (16 KB)
  __syncthreads();

  // hfrag write coordinates (n fixed per thread):
  const int wkt    = n >> 5;
  const int lanehi = ((n >> 3) & 3) * 16;
  const int we     = n & 7;

  for (int t = 0; t < T; ++t) {
    // prologue: issue chunks 0..2 into ring slots 0..2
    #pragma unroll
    for (int sl = 0; sl < 3; ++sl)
      gload_lds16(UB + sl * 512, ring + sl * 512);

    f32x4 acc[4][2];
    #pragma unroll
    for (int g = 0; g < 4; ++g) { acc[g][0] = f32x4{0,0,0,0}; acc[g][1] = f32x4{0,0,0,0}; }

    f16x8 a0, a1;
    #pragma unroll
    for (int kt = 0; kt < 8; ++kt) {
      #pragma unroll
      for (int g = 0; g < 4; ++g) {
        const int cc = kt * 4 + g;
        asm volatile("s_waitcnt vmcnt(2)" ::: "memory");   // chunk cc landed
        if (g == 0) {
          a0 = *(const f16x8*)(hfrag + (0 * 8 + kt) * 512 + l * 8);
          a1 = *(const f16x8*)(hfrag + (1 * 8 + kt) * 512 + l * 8);
        }
        const f16x8 Bv = *(const f16x8*)(ring + (cc % 3) * 512 + l * 8);
        __builtin_amdgcn_sched_barrier(0);                 // pin read-before-refill
        if (cc + 3 < 32)
          gload_lds16(UB + (cc + 3) * 512, ring + (cc % 3) * 512);
        acc[g][0] = __builtin_amdgcn_mfma_f32_16x16x32_f16(a0, Bv, acc[g][0], 0, 0, 0);
        acc[g][1] = __builtin_amdgcn_mfma_f32_16x16x32_f16(a1, Bv, acc[g][1], 0, 0, 0);
      }
    }
    __syncthreads();   // all waves done reading hfrag

    #pragma unroll
    for (int mt = 0; mt < 2; ++mt) {
      float4 xq;
      float4 yq[4];
      if (!isY) {
        xq = *(const float4*)(xrow + t * 32 + mt * 16 + lq * 4);
      } else {
        #pragma unroll
        for (int g = 0; g < 4; ++g)
          yq[g] = *(const float4*)(yg0t + ((size_t)t * 1024 + g * 256 + n) * 32 + mt * 16 + lq * 4);
      }
      #pragma unroll
      for (int j = 0; j < 4; ++j) {
        const int b = mt * 16 + lq * 4 + j;
        float p0, p1, p2, p3;
        if (isY) {
          p0 = acc[0][mt][j] + ((const float*)&yq[0])[j];
          p1 = acc[1][mt][j] + ((const float*)&yq[1])[j];
          p2 = acc[2][mt][j] + ((const float*)&yq[2])[j];
          p3 = acc[3][mt][j] + ((const float*)&yq[3])[j];
        } else {
          const float x = ((const float*)&xq)[j];
          p0 = acc[0][mt][j] + x * Wc[0] + Bc[0];
          p1 = acc[1][mt][j] + x * Wc[1] + Bc[1];
          p2 = acc[2][mt][j] + x * Wc[2] + Bc[2];
          p3 = acc[3][mt][j] + x * Wc[3] + Bc[3];
        }
        const float ig = sigm(p0), fg = sigm(p1), gy = ftanh(p2), og = sigm(p3);
        c2[mt][j] = fg * c2[mt][j] + ig * gy;
        const float h = og * ftanh(c2[mt][j]);
        const int lanep = (lq * 4 + j) + lanehi;
        hfrag[(mt * 8 + wkt) * 512 + lanep * 8 + we] = (f16)h;
        if (isY) Yh[((size_t)b * T + t) * H + n] = h;
        else hout[(((size_t)t * 32 + b) * 256) + n] = (f16)h;
      }
    }
    __syncthreads();   // h visible for next step's reads
  }
}

// ---------------------------------------------------------------------------
// k_mean: feature mean. Ph[(b*T+t)*H+n] = mean_f hseq[f][t][b][n] (f=0..31),
// Nh from f=32..63.
// ---------------------------------------------------------------------------
__global__ __launch_bounds__(256) void k_mean(
    const f16* __restrict__ hseq, float* __restrict__ Ph, float* __restrict__ Nh)
{
  const int bt = blockIdx.x;        // b*T + t
  const int b = bt >> 6, t = bt & 63;
  const int n = threadIdx.x;
  const size_t base = (((size_t)t * 32 + b) * 256) + n;
  float s0 = 0.f, s1 = 0.f;
  #pragma unroll
  for (int f = 0; f < 32; ++f) {
    s0 += (float)hseq[(size_t)f        * (64 * 32 * 256) + base];
    s1 += (float)hseq[(size_t)(f + 32) * (64 * 32 * 256) + base];
  }
  Ph[(size_t)bt * 256 + n] = s0 * 0.03125f;
  Nh[(size_t)bt * 256 + n] = s1 * 0.03125f;
}

// ---------------------------------------------------------------------------
// k_xg: MI-LSTM input projections.
// ---------------------------------------------------------------------------
__global__ __launch_bounds__(1024) void k_xg(
    const float* __restrict__ Yh, const float* __restrict__ Ph, const float* __restrict__ Nh,
    const float* __restrict__ Wm, const float* __restrict__ bm,
    const float* __restrict__ Wpa, const float* __restrict__ bpa,
    const float* __restrict__ Wna, const float* __restrict__ bna,
    float* __restrict__ yg, float* __restrict__ pg, float* __restrict__ ng)
{
  __shared__ __align__(16) float A[8][768];
  const int tid = threadIdx.x;
  const int ro  = blockIdx.x * 8;

  for (int idx = tid; idx < 8 * 768; idx += 1024) {
    const int r = idx / 768, cc = idx % 768;
    const int row = ro + r;
    float v;
    if (cc < 256)      v = Yh[(size_t)row * H + cc];
    else if (cc < 512) v = Ph[(size_t)row * H + (cc - 256)];
    else               v = Nh[(size_t)row * H + (cc - 512)];
    A[r][cc] = v;
  }
  __syncthreads();

  float acc[8];
  #pragma unroll
  for (int r = 0; r < 8; ++r) acc[r] = bm[tid];
  for (int k = 0; k < H; k += 4) {
    const float w0 = Wm[(k + 0) * 1024 + tid];
    const float w1 = Wm[(k + 1) * 1024 + tid];
    const float w2 = Wm[(k + 2) * 1024 + tid];
    const float w3 = Wm[(k + 3) * 1024 + tid];
    #pragma unroll
    for (int r = 0; r < 8; ++r) {
      const float4 av = *(const float4*)&A[r][k];
      acc[r] += w0 * av.x + w1 * av.y + w2 * av.z + w3 * av.w;
    }
  }
  #pragma unroll
  for (int r = 0; r < 8; ++r) yg[(size_t)(ro + r) * 1024 + tid] = acc[r];

  const int col = tid & 511;
  const float* Wx = (tid < 512) ? Wpa : Wna;
  const float* bx = (tid < 512) ? bpa : bna;
  float* outp     = (tid < 512) ? pg : ng;
  const int aoff  = (tid < 512) ? 256 : 512;
  #pragma unroll
  for (int r = 0; r < 8; ++r) acc[r] = bx[col];
  for (int k = 0; k < H; k += 4) {
    const float w0 = Wx[(k + 0) * 512 + col];
    const float w1 = Wx[(k + 1) * 512 + col];
    const float w2 = Wx[(k + 2) * 512 + col];
    const float w3 = Wx[(k + 3) * 512 + col];
    #pragma unroll
    for (int r = 0; r < 8; ++r) {
      const float4 av = *(const float4*)&A[r][aoff + k];
      acc[r] += w0 * av.x + w1 * av.y + w2 * av.z + w3 * av.w;
    }
  }
  #pragma unroll
  for (int r = 0; r < 8; ++r) outp[(size_t)(ro + r) * 512 + col] = acc[r];
}

// ---------------------------------------------------------------------------
// k_mi v5: one block per batch (32 blocks, 1024 thr), NO cross-block sync.
// Phase1 streams the packed 1.18 MB f16 weight buffer; phase2 does gates /
// cell-attention softmax / state update with in-block reductions.
// ---------------------------------------------------------------------------
__global__ __launch_bounds__(1024, 1) void k_mi(
    const float* __restrict__ yg, const float* __restrict__ pg, const float* __restrict__ ng,
    const f16* __restrict__ Wmi, const float* __restrict__ ba,
    float* __restrict__ Hm)
{
  __shared__ float g_all[2304];
  __shared__ __align__(16) f16 h_lds[256];
  __shared__ __align__(16) f16 c_lds[256];
  __shared__ float red[3][4];
  const int tid = threadIdx.x;
  const int b = blockIdx.x;

  if (tid < 256) { h_lds[tid] = (f16)0.f; c_lds[tid] = (f16)0.f; }
  const float bav = (tid < 256) ? ba[tid] : 0.f;
  float creg = 0.f;
  __syncthreads();

  for (int t = 0; t < T; ++t) {
    const size_t row = (size_t)b * T + t;

    float pre[8];
    if (tid < 256) {
      #pragma unroll
      for (int g = 0; g < 4; ++g) pre[g] = yg[row * 1024 + g * 256 + tid];
      pre[4] = pg[row * 512 + tid];       pre[5] = pg[row * 512 + 256 + tid];
      pre[6] = ng[row * 512 + tid];       pre[7] = ng[row * 512 + 256 + tid];
    }

    for (int c = tid; c < 2304; c += 1024) {
      const f16* hsrc = (c >= 2048) ? c_lds : h_lds;
      const f16* wcol = Wmi + (size_t)c * 8;
      float acc = 0.f;
      #pragma unroll 8
      for (int kc = 0; kc < 32; ++kc) {
        const f16x8 wv = *(const f16x8*)(wcol + (size_t)kc * 2304 * 8);
        const f16x8 hv = *(const f16x8*)(hsrc + kc * 8);
        #pragma unroll
        for (int e = 0; e < 8; ++e) acc += (float)wv[e] * (float)hv[e];
      }
      g_all[c] = acc;
    }
    __syncthreads();

    float l0 = 0.f, l1 = 0.f, l2 = 0.f, fg = 0.f, og = 0.f;
    if (tid < 256) {
      const int n = tid;
      const float gi = sigm(g_all[n]            + pre[0]);
      fg             = sigm(g_all[256 + n]      + pre[1]);
      const float gy = ftanh(g_all[512 + n]     + pre[2]);
      og             = sigm(g_all[768 + n]      + pre[3]);
      const float ip = sigm(g_all[1024 + n]     + pre[4]);
      const float cp = ftanh(g_all[1280 + n]    + pre[5]);
      const float in = sigm(g_all[1536 + n]     + pre[6]);
      const float cn = ftanh(g_all[1792 + n]    + pre[7]);
      const float att = ftanh(g_all[2048 + n]   + bav);
      l0 = gi * gy; l1 = ip * cp; l2 = in * cn;
      float v0 = l0 * att, v1 = l1 * att, v2 = l2 * att;
      #pragma unroll
      for (int off = 32; off; off >>= 1) {
        v0 += __shfl_down(v0, off);
        v1 += __shfl_down(v1, off);
        v2 += __shfl_down(v2, off);
      }
      if ((tid & 63) == 0) {
        red[0][tid >> 6] = v0; red[1][tid >> 6] = v1; red[2][tid >> 6] = v2;
      }
    }
    __syncthreads();

    if (tid < 256) {
      const int n = tid;
      const float s0 = red[0][0] + red[0][1] + red[0][2] + red[0][3];
      const float s1 = red[1][0] + red[1][1] + red[1][2] + red[1][3];
      const float s2 = red[2][0] + red[2][1] + red[2][2] + red[2][3];
      const float m  = fmaxf(s0, fmaxf(s1, s2));
      const float e0 = __expf(s0 - m), e1 = __expf(s1 - m), e2 = __expf(s2 - m);
      const float lt = (e0 * l0 + e1 * l1 + e2 * l2) / (e0 + e1 + e2);
      creg = fg * creg + lt;
      const float h = og * ftanh(creg);
      h_lds[n] = (f16)h;
      c_lds[n] = (f16)creg;
      Hm[row * H + n] = h;
    }
    __syncthreads();
  }
}

// ---------------------------------------------------------------------------
// k_att: temporal additive attention + linear head.
// ---------------------------------------------------------------------------
__global__ __launch_bounds__(256) void k_att(
    const float* __restrict__ Hm, const float* __restrict__ Watt, const float* __restrict__ batt,
    const float* __restrict__ vatt, const float* __restrict__ Wlin, const float* __restrict__ blin,
    float* __restrict__ out)
{
  __shared__ __align__(16) float hm8[8][H];
  __shared__ float vred[8][4];
  __shared__ float s_lds[T];
  __shared__ float alpha_lds[T];
  __shared__ float red4[4];
  const int n = threadIdx.x;
  const int b = blockIdx.x;
  const float bn = batt[n], vn = vatt[n];

  for (int t0 = 0; t0 < T; t0 += 8) {
    __syncthreads();
    #pragma unroll
    for (int r = 0; r < 8; ++r) hm8[r][n] = Hm[((size_t)b * T + t0 + r) * H + n];
    __syncthreads();
    float acc[8];
    #pragma unroll
    for (int r = 0; r < 8; ++r) acc[r] = bn;
    for (int k = 0; k < H; k += 4) {
      const float w0 = Watt[(k + 0) * H + n];
      const float w1 = Watt[(k + 1) * H + n];
      const float w2 = Watt[(k + 2) * H + n];
      const float w3 = Watt[(k + 3) * H + n];
      #pragma unroll
      for (int r = 0; r < 8; ++r) {
        const float4 hv = *(const float4*)&hm8[r][k];
        acc[r] += w0 * hv.x + w1 * hv.y + w2 * hv.z + w3 * hv.w;
      }
    }
    #pragma unroll
    for (int r = 0; r < 8; ++r) {
      float v = tanhf(acc[r]) * vn;
      for (int off = 32; off; off >>= 1) v += __shfl_down(v, off);
      if ((n & 63) == 0) vred[r][n >> 6] = v;
    }
    __syncthreads();
    if (n < 8) s_lds[t0 + n] = vred[n][0] + vred[n][1] + vred[n][2] + vred[n][3];
  }
  __syncthreads();

  if (n < T) {
    const float sv = s_lds[n];
    float m = sv;
    for (int off = 32; off; off >>= 1) m = fmaxf(m, __shfl_xor(m, off));
    const float e = expf(sv - m);
    float sum = e;
    for (int off = 32; off; off >>= 1) sum += __shfl_xor(sum, off);
    alpha_lds[n] = e / sum;
  }
  __syncthreads();

  float acc = 0.f;
  for (int t = 0; t < T; ++t) acc += alpha_lds[t] * Hm[((size_t)b * T + t) * H + n];
  float p = acc * Wlin[n];
  for (int off = 32; off; off >>= 1) p += __shfl_down(p, off);
  if ((n & 63) == 0) red4[n >> 6] = p;
  __syncthreads();
  if (n == 0) out[b] = fmaxf(red4[0] + red4[1] + red4[2] + red4[3] + blin[0], 0.f);
}

// ---------------------------------------------------------------------------
extern "C" void kernel_launch(void* const* d_in, const int* in_sizes, int n_in,
                              void* d_out, int out_size, void* d_ws, size_t ws_size,
                              hipStream_t stream) {
  const float* Yin  = (const float*)d_in[0];
  const float* Xp   = (const float*)d_in[1];
  const float* Xn   = (const float*)d_in[2];
  const float* Wy   = (const float*)d_in[3];
  const float* Uy   = (const float*)d_in[4];
  const float* by   = (const float*)d_in[5];
  const float* Wxp  = (const float*)d_in[6];
  const float* Uxp  = (const float*)d_in[7];
  const float* bxp  = (const float*)d_in[8];
  const float* Wxn  = (const float*)d_in[9];
  const float* Uxn  = (const float*)d_in[10];
  const float* bxn  = (const float*)d_in[11];
  const float* Wm   = (const float*)d_in[12];
  const float* Um   = (const float*)d_in[13];
  const float* bm   = (const float*)d_in[14];
  const float* Wpa  = (const float*)d_in[15];
  const float* Upa  = (const float*)d_in[16];
  const float* bpa  = (const float*)d_in[17];
  const float* Wna  = (const float*)d_in[18];
  const float* Una  = (const float*)d_in[19];
  const float* bna  = (const float*)d_in[20];
  const float* Wa   = (const float*)d_in[21];
  const float* ba   = (const float*)d_in[22];
  const float* Watt = (const float*)d_in[23];
  const float* batt = (const float*)d_in[24];
  const float* vatt = (const float*)d_in[25];
  const float* Wlin = (const float*)d_in[26];
  const float* blin = (const float*)d_in[27];

  float* ws = (float*)d_ws;
  float*    Yh    = ws;                         // 524288
  float*    Ph    = ws + 524288;                // 524288
  float*    Nh    = ws + 1048576;               // 524288
  float*    Hm    = ws + 1572864;               // 524288
  float*    yg    = ws + 2097152;               // 2097152
  float*    pg    = ws + 4194304;               // 1048576
  float*    ng    = ws + 5242880;               // 1048576
  float*    yg0t  = ws + 6291456;               // 2097152
  float*    Xt    = ws + 8388608;               // 131072
  f16*      Uf2   = (f16*)(ws + 8519680);       // 17039360 f16 (8519680 floats)
  f16*      Wmi   = (f16*)(ws + 17039360);      // 589824 f16 (294912 floats)
  f16*      hseq  = (f16*)(ws + 17334272);      // 64*64*32*256 f16 (16777216 floats)
  float*    out   = (float*)d_out;

  k_prep_u   <<<520, 256, 0, stream>>>(Uxp, Uxn, Uy, Uf2);
  k_prep_wmi <<<1152, 64, 0, stream>>>(Um, Upa, Una, Wa, Wmi);
  k_prep_x   <<<64, 512, 0, stream>>>(Xp, Xn, Xt);
  k_prep_yg0 <<<64, 1024, 0, stream>>>(Yin, Wy, by, yg0t);

  k_scan<<<65, 1024, 0, stream>>>(Xt, Wxp, bxp, Wxn, bxn, Uf2, yg0t, Yh, hseq);
  k_mean<<<2048, 256, 0, stream>>>(hseq, Ph, Nh);
  k_xg  <<<256, 1024, 0, stream>>>(Yh, Ph, Nh, Wm, bm, Wpa, bpa, Wna, bna, yg, pg, ng);
  k_mi  <<<32, 1024, 0, stream>>>(yg, pg, ng, Wmi, ba, Hm);
  k_att <<<32, 256, 0, stream>>>(Hm, Watt, batt, vatt, Wlin, blin, out);
}